// Round 2
// baseline (656.825 us; speedup 1.0000x reference)
//
#include <hip/hip_runtime.h>

// Problem constants: B=2, S=2048, D=1024, H=16, DH=64
constexpr int BB = 2, SS = 2048, DD = 1024, HH = 16, DHH = 64;

typedef __attribute__((ext_vector_type(4))) float f32x4;
typedef __attribute__((ext_vector_type(8))) __bf16 bf16x8;      // 4 VGPRs, MFMA A/B operand
typedef __attribute__((ext_vector_type(8))) unsigned short us8; // 16B staging vector

__device__ __forceinline__ unsigned short f32_to_bf16(float f) {
    unsigned int u = __float_as_uint(f);
    u += 0x7fffu + ((u >> 16) & 1u);   // round-to-nearest-even
    return (unsigned short)(u >> 16);
}
__device__ __forceinline__ float bf16_to_f32(unsigned int bits) {
    return __uint_as_float(bits << 16);
}

__device__ __forceinline__ f32x4 mfma_bf16(bf16x8 a, bf16x8 b, f32x4 c) {
    return __builtin_amdgcn_mfma_f32_16x16x32_bf16(a, b, c, 0, 0, 0);
}

// ---------------------------------------------------------------------------
// NT GEMM: C[m][n] = (sum_k A[m][k]*W[n][k] + bias[n]) * scale
// W: N x K fp32 row-major, converted to bf16 during LDS staging.
// MODE 0: A fp32; write bf16 to (B,H,S,DH) layout      (q, k)
// MODE 1: A fp32; write bf16 to (B,H,DH,S) layout      (v transposed for PV)
// MODE 2: A bf16 (ctx); write fp32 row-major M x N     (final output)
// Tile 64x64, BK=64, 4 waves. MFMA 16x16x32 bf16 layouts (m89/m91):
//   A/B: idx=lane&15, k=(lane>>4)*8+j   C/D: col=lane&15, row=(lane>>4)*4+reg
// ---------------------------------------------------------------------------
template <int MODE>
__global__ __launch_bounds__(256) void gemm_nt(const void* __restrict__ Ap,
                                               const float* __restrict__ W,
                                               const float* __restrict__ bias,
                                               void* __restrict__ outp,
                                               float scale) {
    constexpr int K = DD;
    __shared__ __align__(16) unsigned short Ash[64][72];  // +8 pad
    __shared__ __align__(16) unsigned short Bsh[64][72];

    const int m0 = blockIdx.x * 64;
    const int n0 = blockIdx.y * 64;
    const int t = threadIdx.x;
    const int lane = t & 63;
    const int w = t >> 6;
    const int l15 = lane & 15;
    const int quad = lane >> 4;

    f32x4 acc[4] = {};

    for (int k0 = 0; k0 < K; k0 += 64) {
        __syncthreads();
        // W staging: fp32 -> bf16, 64x64 tile, 4 sub-iters of float4
#pragma unroll
        for (int hf = 0; hf < 4; ++hf) {
            const int v = t + hf * 256;
            const int row = v >> 4, c4 = (v & 15) * 4;
            const float4 wv = *(const float4*)&W[(size_t)(n0 + row) * K + k0 + c4];
            ushort4 wb;
            wb.x = f32_to_bf16(wv.x); wb.y = f32_to_bf16(wv.y);
            wb.z = f32_to_bf16(wv.z); wb.w = f32_to_bf16(wv.w);
            *(ushort4*)&Bsh[row][c4] = wb;
        }
        // A staging
        if (MODE == 2) {
            const unsigned short* A = (const unsigned short*)Ap;
#pragma unroll
            for (int hf = 0; hf < 2; ++hf) {
                const int v = t + hf * 256;
                const int row = v >> 3, off = (v & 7) * 8;
                *(us8*)&Ash[row][off] = *(const us8*)&A[(size_t)(m0 + row) * K + k0 + off];
            }
        } else {
            const float* A = (const float*)Ap;
#pragma unroll
            for (int hf = 0; hf < 4; ++hf) {
                const int v = t + hf * 256;
                const int row = v >> 4, c4 = (v & 15) * 4;
                const float4 av = *(const float4*)&A[(size_t)(m0 + row) * K + k0 + c4];
                ushort4 ab;
                ab.x = f32_to_bf16(av.x); ab.y = f32_to_bf16(av.y);
                ab.z = f32_to_bf16(av.z); ab.w = f32_to_bf16(av.w);
                *(ushort4*)&Ash[row][c4] = ab;
            }
        }
        __syncthreads();

        const bf16x8 a0 = *(const bf16x8*)&Ash[w * 16 + l15][quad * 8];
        const bf16x8 a1 = *(const bf16x8*)&Ash[w * 16 + l15][32 + quad * 8];
#pragma unroll
        for (int nt = 0; nt < 4; ++nt) {
            const bf16x8 b0 = *(const bf16x8*)&Bsh[nt * 16 + l15][quad * 8];
            const bf16x8 b1 = *(const bf16x8*)&Bsh[nt * 16 + l15][32 + quad * 8];
            acc[nt] = mfma_bf16(a0, b0, acc[nt]);
            acc[nt] = mfma_bf16(a1, b1, acc[nt]);
        }
    }

#pragma unroll
    for (int nt = 0; nt < 4; ++nt) {
        const int c = n0 + nt * 16 + l15;
        const float bs = bias[c];
#pragma unroll
        for (int r = 0; r < 4; ++r) {
            const int mrow = m0 + w * 16 + quad * 4 + r;
            const float val = (acc[nt][r] + bs) * scale;
            if (MODE == 2) {
                ((float*)outp)[(size_t)mrow * DD + c] = val;
            } else {
                const int bi = mrow >> 11, si = mrow & (SS - 1);
                const int hi = c >> 6, di = c & (DHH - 1);
                unsigned short* o = (unsigned short*)outp;
                if (MODE == 0)
                    o[((size_t)(bi * HH + hi) * SS + si) * DHH + di] = f32_to_bf16(val);
                else
                    o[((size_t)(bi * HH + hi) * DHH + di) * SS + si] = f32_to_bf16(val);
            }
        }
    }
}

// ---------------------------------------------------------------------------
// Flash attention: one workgroup per (b, h, 64-query tile). 4 waves x 16 rows.
// ---------------------------------------------------------------------------
__global__ __launch_bounds__(256) void flash_attn(const unsigned short* __restrict__ qws,
                                                  const unsigned short* __restrict__ kws,
                                                  const unsigned short* __restrict__ vws,
                                                  const int* __restrict__ mask,
                                                  unsigned short* __restrict__ ctx) {
    __shared__ __align__(16) unsigned short Ksh[64][72];      // [key][d]
    __shared__ __align__(16) unsigned short Vsh[64][72];      // [d][key] (pre-transposed)
    __shared__ __align__(16) unsigned short Psh[4][16][72];   // per-wave P tile [q][key]

    constexpr int NQT = SS / 64;
    const int qt = blockIdx.x % NQT;
    const int bh = blockIdx.x / NQT;
    const int bi = bh / HH, hi = bh % HH;

    const int t = threadIdx.x;
    const int lane = t & 63, w = t >> 6;
    const int l15 = lane & 15, quad = lane >> 4;

    const unsigned short* qp = qws + (size_t)bh * SS * DHH;
    const unsigned short* kp = kws + (size_t)bh * SS * DHH;
    const unsigned short* vp = vws + (size_t)bh * DHH * SS;

    const int qrow0 = qt * 64 + w * 16;
    const bf16x8 aq0 = *(const bf16x8*)(qp + (size_t)(qrow0 + l15) * DHH + quad * 8);
    const bf16x8 aq1 = *(const bf16x8*)(qp + (size_t)(qrow0 + l15) * DHH + 32 + quad * 8);

    f32x4 accO[4] = {};
    float m_run[4], l_run[4];
#pragma unroll
    for (int r = 0; r < 4; ++r) { m_run[r] = -1e30f; l_run[r] = 0.f; }

    const int* mbase = mask + ((size_t)bi * SS + qrow0 + quad * 4) * SS;
    const float NEG_INF = -__builtin_inff();

    for (int kt = 0; kt < SS / 64; ++kt) {
        __syncthreads();   // previous iteration's LDS reads done before restage
#pragma unroll
        for (int hf = 0; hf < 2; ++hf) {
            const int v = t + hf * 256;
            const int row = v >> 3, off = (v & 7) * 8;
            *(us8*)&Ksh[row][off] = *(const us8*)(kp + (size_t)(kt * 64 + row) * DHH + off);
            *(us8*)&Vsh[row][off] = *(const us8*)(vp + (size_t)row * SS + kt * 64 + off);
        }
        __syncthreads();

        // QK^T: scores[q][key], 4 tiles of 16 keys, 2 k-steps over DH=64
        float sc[4][4];
#pragma unroll
        for (int nt = 0; nt < 4; ++nt) {
            const bf16x8 b0 = *(const bf16x8*)&Ksh[nt * 16 + l15][quad * 8];
            const bf16x8 b1 = *(const bf16x8*)&Ksh[nt * 16 + l15][32 + quad * 8];
            f32x4 s4 = {};
            s4 = mfma_bf16(aq0, b0, s4);
            s4 = mfma_bf16(aq1, b1, s4);
#pragma unroll
            for (int r = 0; r < 4; ++r) sc[nt][r] = s4[r];
        }

        // mask (nonzero -> -inf); mask[b][q][k] int32
#pragma unroll
        for (int r = 0; r < 4; ++r) {
            const int* mr = mbase + (size_t)r * SS + kt * 64;
#pragma unroll
            for (int nt = 0; nt < 4; ++nt)
                if (mr[nt * 16 + l15] != 0) sc[nt][r] = NEG_INF;
        }

        // online softmax update
#pragma unroll
        for (int r = 0; r < 4; ++r) {
            float tm = fmaxf(fmaxf(sc[0][r], sc[1][r]), fmaxf(sc[2][r], sc[3][r]));
            tm = fmaxf(tm, __shfl_xor(tm, 1));
            tm = fmaxf(tm, __shfl_xor(tm, 2));
            tm = fmaxf(tm, __shfl_xor(tm, 4));
            tm = fmaxf(tm, __shfl_xor(tm, 8));
            const float mn = fmaxf(m_run[r], tm);     // m_init=-1e30 keeps this finite
            const float alpha = __expf(m_run[r] - mn);
            float rs = 0.f;
#pragma unroll
            for (int nt = 0; nt < 4; ++nt) {
                const float p = __expf(sc[nt][r] - mn);   // exp(-inf)=0 for masked
                sc[nt][r] = p;
                rs += p;
            }
            rs += __shfl_xor(rs, 1);
            rs += __shfl_xor(rs, 2);
            rs += __shfl_xor(rs, 4);
            rs += __shfl_xor(rs, 8);
            l_run[r] = l_run[r] * alpha + rs;
            m_run[r] = mn;
#pragma unroll
            for (int nt = 0; nt < 4; ++nt) accO[nt][r] *= alpha;
        }

        // P: C-layout -> LDS -> A-layout (m120 pattern), per-wave buffer
#pragma unroll
        for (int nt = 0; nt < 4; ++nt)
#pragma unroll
            for (int r = 0; r < 4; ++r)
                Psh[w][quad * 4 + r][nt * 16 + l15] = f32_to_bf16(sc[nt][r]);
        __asm__ volatile("s_waitcnt lgkmcnt(0)" ::: "memory");  // wave-local RAW on Psh

        const bf16x8 p0 = *(const bf16x8*)&Psh[w][l15][quad * 8];
        const bf16x8 p1 = *(const bf16x8*)&Psh[w][l15][32 + quad * 8];
#pragma unroll
        for (int nt = 0; nt < 4; ++nt) {
            const bf16x8 v0 = *(const bf16x8*)&Vsh[nt * 16 + l15][quad * 8];
            const bf16x8 v1 = *(const bf16x8*)&Vsh[nt * 16 + l15][32 + quad * 8];
            accO[nt] = mfma_bf16(p0, v0, accO[nt]);
            accO[nt] = mfma_bf16(p1, v1, accO[nt]);
        }
    }

    // epilogue: normalize, write ctx in (B,S,D) bf16 (row-major for final GEMM)
#pragma unroll
    for (int r = 0; r < 4; ++r) {
        const float inv = 1.0f / l_run[r];
        const int gq = bi * SS + qrow0 + quad * 4 + r;
#pragma unroll
        for (int nt = 0; nt < 4; ++nt)
            ctx[(size_t)gq * DD + hi * DHH + nt * 16 + l15] = f32_to_bf16(accO[nt][r] * inv);
    }
}

// ---------------------------------------------------------------------------
// top_attn: full softmax(masked head-0 scores) -> d_out tail.
// Reads the 1 MB head-0 q/k copies in d_ws (its own output region overwrites
// the scratch where q/k originally lived).
// ---------------------------------------------------------------------------
__global__ __launch_bounds__(256) void top_attn(const unsigned short* __restrict__ q0,
                                                const unsigned short* __restrict__ k0,
                                                const int* __restrict__ mask,
                                                float* __restrict__ outp) {
    __shared__ float qf[DHH];
    __shared__ float scb[SS];
    __shared__ float wred[4];

    const int bi = blockIdx.x / SS;
    const int qi = blockIdx.x % SS;
    const int t = threadIdx.x;

    const unsigned short* qp = q0 + ((size_t)bi * SS + qi) * DHH;
    if (t < DHH) qf[t] = bf16_to_f32(qp[t]);
    __syncthreads();

    const unsigned short* kp = k0 + (size_t)bi * SS * DHH;
    const int* mr = mask + ((size_t)bi * SS + qi) * SS;
    const float NEG_INF = -__builtin_inff();

    float lmax = NEG_INF;
#pragma unroll
    for (int i = 0; i < 8; ++i) {
        const int key = t + i * 256;
        const unsigned int* kr = (const unsigned int*)(kp + (size_t)key * DHH);
        float s = 0.f;
#pragma unroll
        for (int d2 = 0; d2 < 32; ++d2) {
            const unsigned int u = kr[d2];
            s += qf[2 * d2] * __uint_as_float(u << 16);
            s += qf[2 * d2 + 1] * __uint_as_float(u & 0xffff0000u);
        }
        if (mr[key] != 0) s = NEG_INF;
        scb[key] = s;
        lmax = fmaxf(lmax, s);
    }
#pragma unroll
    for (int m = 1; m < 64; m <<= 1) lmax = fmaxf(lmax, __shfl_xor(lmax, m));
    if ((t & 63) == 0) wred[t >> 6] = lmax;
    __syncthreads();
    const float bmax = fmaxf(fmaxf(wred[0], wred[1]), fmaxf(wred[2], wred[3]));
    __syncthreads();

    float lsum = 0.f;
#pragma unroll
    for (int i = 0; i < 8; ++i) {
        const int key = t + i * 256;
        const float p = __expf(scb[key] - bmax);
        scb[key] = p;
        lsum += p;
    }
#pragma unroll
    for (int m = 1; m < 64; m <<= 1) lsum += __shfl_xor(lsum, m);
    if ((t & 63) == 0) wred[t >> 6] = lsum;
    __syncthreads();
    const float inv = 1.0f / (wred[0] + wred[1] + wred[2] + wred[3]);

    float* orow = outp + ((size_t)bi * SS + qi) * SS;
#pragma unroll
    for (int i = 0; i < 8; ++i) {
        const int key = t + i * 256;
        orow[key] = scb[key] * inv;
    }
}

// ---------------------------------------------------------------------------
// inputs: 0 key, 1 value, 2 query, 3 mask, 4 Wk, 5 bk, 6 Wv, 7 bv,
//         8 Wq, 9 bq, 10 Wo, 11 bo
// d_out: output (B*S*D f32) ++ top_attn (B*S*S f32)
//
// Scratch plan (d_ws may be small — use only 1 MB of it):
//   qws/kws/vws/ctx (32 MB bf16) live inside d_out's top_attn region, which
//   is only written by the FINAL top_attn kernel. d_ws holds just the 1 MB
//   head-0 q/k slices top_attn needs after its region is overwritten.
// ---------------------------------------------------------------------------
extern "C" void kernel_launch(void* const* d_in, const int* in_sizes, int n_in,
                              void* d_out, int out_size, void* d_ws, size_t ws_size,
                              hipStream_t stream) {
    const float* key_   = (const float*)d_in[0];
    const float* value_ = (const float*)d_in[1];
    const float* query_ = (const float*)d_in[2];
    const int*   mask_  = (const int*)d_in[3];
    const float* Wk = (const float*)d_in[4];
    const float* bk = (const float*)d_in[5];
    const float* Wv = (const float*)d_in[6];
    const float* bv = (const float*)d_in[7];
    const float* Wq = (const float*)d_in[8];
    const float* bq = (const float*)d_in[9];
    const float* Wo = (const float*)d_in[10];
    const float* bo = (const float*)d_in[11];

    constexpr size_t XS = (size_t)BB * SS * DD;   // 4194304 elements

    float* out_f = (float*)d_out;
    // bf16 scratch inside d_out[XS .. XS + 2*B*S*S/... ) — the 8M-float
    // top_attn region holds exactly 16M bf16 = qws+kws+vws+ctx.
    unsigned short* scratch = (unsigned short*)(out_f + XS);
    unsigned short* qws = scratch;            // (B,H,S,DH)
    unsigned short* kws = qws + XS;           // (B,H,S,DH)
    unsigned short* vws = kws + XS;           // (B,H,DH,S)
    unsigned short* ctx = vws + XS;           // (B,S,D)

    unsigned short* q0 = (unsigned short*)d_ws;        // [B][S][DH] head-0 q
    unsigned short* k0 = q0 + (size_t)BB * SS * DHH;   // [B][S][DH] head-0 k

    dim3 gg(BB * SS / 64, DD / 64);
    gemm_nt<0><<<gg, 256, 0, stream>>>(query_, Wq, bq, qws, 0.125f);  // 1/sqrt(DH) folded
    gemm_nt<0><<<gg, 256, 0, stream>>>(key_,   Wk, bk, kws, 1.0f);
    gemm_nt<1><<<gg, 256, 0, stream>>>(value_, Wv, bv, vws, 1.0f);    // v transposed

    // save head-0 q/k (contiguous slices) into d_ws before scratch is clobbered
    for (int b = 0; b < BB; ++b) {
        hipMemcpyAsync(q0 + (size_t)b * SS * DHH, qws + (size_t)(b * HH) * SS * DHH,
                       (size_t)SS * DHH * sizeof(unsigned short),
                       hipMemcpyDeviceToDevice, stream);
        hipMemcpyAsync(k0 + (size_t)b * SS * DHH, kws + (size_t)(b * HH) * SS * DHH,
                       (size_t)SS * DHH * sizeof(unsigned short),
                       hipMemcpyDeviceToDevice, stream);
    }

    flash_attn<<<BB * HH * (SS / 64), 256, 0, stream>>>(qws, kws, vws, mask_, ctx);

    gemm_nt<2><<<gg, 256, 0, stream>>>(ctx, Wo, bo, out_f, 1.0f);

    // LAST: overwrites the scratch region with the real top_attn output
    top_attn<<<BB * SS, 256, 0, stream>>>(q0, k0, mask_, out_f + XS);
}

// Round 3
// 532.921 us; speedup vs baseline: 1.2325x; 1.2325x over previous
//
#include <hip/hip_runtime.h>

// Problem constants: B=2, S=2048, D=1024, H=16, DH=64
constexpr int BB = 2, SS = 2048, DD = 1024, HH = 16, DHH = 64;

typedef __attribute__((ext_vector_type(4))) float f32x4;
typedef __attribute__((ext_vector_type(8))) __bf16 bf16x8;      // 4 VGPRs, MFMA A/B operand
typedef __attribute__((ext_vector_type(8))) unsigned short us8; // 16B staging vector

__device__ __forceinline__ unsigned short f32_to_bf16(float f) {
    unsigned int u = __float_as_uint(f);
    u += 0x7fffu + ((u >> 16) & 1u);   // round-to-nearest-even
    return (unsigned short)(u >> 16);
}
__device__ __forceinline__ float bf16_to_f32(unsigned int bits) {
    return __uint_as_float(bits << 16);
}

__device__ __forceinline__ f32x4 mfma_bf16(bf16x8 a, bf16x8 b, f32x4 c) {
    return __builtin_amdgcn_mfma_f32_16x16x32_bf16(a, b, c, 0, 0, 0);
}

// ---------------------------------------------------------------------------
// NT GEMM: C[m][n] = (sum_k A[m][k]*W[n][k] + bias[n]) * scale
// W: N x K fp32 row-major, converted to bf16 during LDS staging.
// MODE 0: A fp32; write bf16 to (B,H,S,DH) layout      (q, k)
// MODE 1: A fp32; write bf16 to (B,H,DH,S) layout      (v transposed for PV)
// MODE 2: A bf16 (ctx); write fp32 row-major M x N     (final output)
// Tile 64x64, BK=64, 4 waves. MFMA 16x16x32 bf16 layouts (m89/m91):
//   A/B: idx=lane&15, k=(lane>>4)*8+j   C/D: col=lane&15, row=(lane>>4)*4+reg
// ---------------------------------------------------------------------------
template <int MODE>
__global__ __launch_bounds__(256) void gemm_nt(const void* __restrict__ Ap,
                                               const float* __restrict__ W,
                                               const float* __restrict__ bias,
                                               void* __restrict__ outp,
                                               float scale) {
    constexpr int K = DD;
    __shared__ __align__(16) unsigned short Ash[64][72];  // +8 pad
    __shared__ __align__(16) unsigned short Bsh[64][72];

    const int m0 = blockIdx.x * 64;
    const int n0 = blockIdx.y * 64;
    const int t = threadIdx.x;
    const int lane = t & 63;
    const int w = t >> 6;
    const int l15 = lane & 15;
    const int quad = lane >> 4;

    f32x4 acc[4] = {};

    for (int k0 = 0; k0 < K; k0 += 64) {
        __syncthreads();
        // W staging: fp32 -> bf16, 64x64 tile, 4 sub-iters of float4
#pragma unroll
        for (int hf = 0; hf < 4; ++hf) {
            const int v = t + hf * 256;
            const int row = v >> 4, c4 = (v & 15) * 4;
            const float4 wv = *(const float4*)&W[(size_t)(n0 + row) * K + k0 + c4];
            ushort4 wb;
            wb.x = f32_to_bf16(wv.x); wb.y = f32_to_bf16(wv.y);
            wb.z = f32_to_bf16(wv.z); wb.w = f32_to_bf16(wv.w);
            *(ushort4*)&Bsh[row][c4] = wb;
        }
        // A staging
        if (MODE == 2) {
            const unsigned short* A = (const unsigned short*)Ap;
#pragma unroll
            for (int hf = 0; hf < 2; ++hf) {
                const int v = t + hf * 256;
                const int row = v >> 3, off = (v & 7) * 8;
                *(us8*)&Ash[row][off] = *(const us8*)&A[(size_t)(m0 + row) * K + k0 + off];
            }
        } else {
            const float* A = (const float*)Ap;
#pragma unroll
            for (int hf = 0; hf < 4; ++hf) {
                const int v = t + hf * 256;
                const int row = v >> 4, c4 = (v & 15) * 4;
                const float4 av = *(const float4*)&A[(size_t)(m0 + row) * K + k0 + c4];
                ushort4 ab;
                ab.x = f32_to_bf16(av.x); ab.y = f32_to_bf16(av.y);
                ab.z = f32_to_bf16(av.z); ab.w = f32_to_bf16(av.w);
                *(ushort4*)&Ash[row][c4] = ab;
            }
        }
        __syncthreads();

        const bf16x8 a0 = *(const bf16x8*)&Ash[w * 16 + l15][quad * 8];
        const bf16x8 a1 = *(const bf16x8*)&Ash[w * 16 + l15][32 + quad * 8];
#pragma unroll
        for (int nt = 0; nt < 4; ++nt) {
            const bf16x8 b0 = *(const bf16x8*)&Bsh[nt * 16 + l15][quad * 8];
            const bf16x8 b1 = *(const bf16x8*)&Bsh[nt * 16 + l15][32 + quad * 8];
            acc[nt] = mfma_bf16(a0, b0, acc[nt]);
            acc[nt] = mfma_bf16(a1, b1, acc[nt]);
        }
    }

#pragma unroll
    for (int nt = 0; nt < 4; ++nt) {
        const int c = n0 + nt * 16 + l15;
        const float bs = bias[c];
#pragma unroll
        for (int r = 0; r < 4; ++r) {
            const int mrow = m0 + w * 16 + quad * 4 + r;
            const float val = (acc[nt][r] + bs) * scale;
            if (MODE == 2) {
                ((float*)outp)[(size_t)mrow * DD + c] = val;
            } else {
                const int bi = mrow >> 11, si = mrow & (SS - 1);
                const int hi = c >> 6, di = c & (DHH - 1);
                unsigned short* o = (unsigned short*)outp;
                if (MODE == 0)
                    o[((size_t)(bi * HH + hi) * SS + si) * DHH + di] = f32_to_bf16(val);
                else
                    o[((size_t)(bi * HH + hi) * DHH + di) * SS + si] = f32_to_bf16(val);
            }
        }
    }
}

// ---------------------------------------------------------------------------
// Flash attention: one workgroup per (b, h, 64-query tile). 4 waves x 16 rows.
// ---------------------------------------------------------------------------
__global__ __launch_bounds__(256) void flash_attn(const unsigned short* __restrict__ qws,
                                                  const unsigned short* __restrict__ kws,
                                                  const unsigned short* __restrict__ vws,
                                                  const int* __restrict__ mask,
                                                  unsigned short* __restrict__ ctx) {
    __shared__ __align__(16) unsigned short Ksh[64][72];      // [key][d]
    __shared__ __align__(16) unsigned short Vsh[64][72];      // [d][key] (pre-transposed)
    __shared__ __align__(16) unsigned short Psh[4][16][72];   // per-wave P tile [q][key]

    constexpr int NQT = SS / 64;
    const int qt = blockIdx.x % NQT;
    const int bh = blockIdx.x / NQT;
    const int bi = bh / HH, hi = bh % HH;

    const int t = threadIdx.x;
    const int lane = t & 63, w = t >> 6;
    const int l15 = lane & 15, quad = lane >> 4;

    const unsigned short* qp = qws + (size_t)bh * SS * DHH;
    const unsigned short* kp = kws + (size_t)bh * SS * DHH;
    const unsigned short* vp = vws + (size_t)bh * DHH * SS;

    const int qrow0 = qt * 64 + w * 16;
    const bf16x8 aq0 = *(const bf16x8*)(qp + (size_t)(qrow0 + l15) * DHH + quad * 8);
    const bf16x8 aq1 = *(const bf16x8*)(qp + (size_t)(qrow0 + l15) * DHH + 32 + quad * 8);

    f32x4 accO[4] = {};
    float m_run[4], l_run[4];
#pragma unroll
    for (int r = 0; r < 4; ++r) { m_run[r] = -1e30f; l_run[r] = 0.f; }

    const int* mbase = mask + ((size_t)bi * SS + qrow0 + quad * 4) * SS;
    const float NEG_INF = -__builtin_inff();

    for (int kt = 0; kt < SS / 64; ++kt) {
        __syncthreads();   // previous iteration's LDS reads done before restage
#pragma unroll
        for (int hf = 0; hf < 2; ++hf) {
            const int v = t + hf * 256;
            const int row = v >> 3, off = (v & 7) * 8;
            *(us8*)&Ksh[row][off] = *(const us8*)(kp + (size_t)(kt * 64 + row) * DHH + off);
            *(us8*)&Vsh[row][off] = *(const us8*)(vp + (size_t)row * SS + kt * 64 + off);
        }
        __syncthreads();

        // QK^T: scores[q][key], 4 tiles of 16 keys, 2 k-steps over DH=64
        float sc[4][4];
#pragma unroll
        for (int nt = 0; nt < 4; ++nt) {
            const bf16x8 b0 = *(const bf16x8*)&Ksh[nt * 16 + l15][quad * 8];
            const bf16x8 b1 = *(const bf16x8*)&Ksh[nt * 16 + l15][32 + quad * 8];
            f32x4 s4 = {};
            s4 = mfma_bf16(aq0, b0, s4);
            s4 = mfma_bf16(aq1, b1, s4);
#pragma unroll
            for (int r = 0; r < 4; ++r) sc[nt][r] = s4[r];
        }

        // mask (nonzero -> -inf); mask[b][q][k] int32
#pragma unroll
        for (int r = 0; r < 4; ++r) {
            const int* mr = mbase + (size_t)r * SS + kt * 64;
#pragma unroll
            for (int nt = 0; nt < 4; ++nt)
                if (mr[nt * 16 + l15] != 0) sc[nt][r] = NEG_INF;
        }

        // online softmax update
#pragma unroll
        for (int r = 0; r < 4; ++r) {
            float tm = fmaxf(fmaxf(sc[0][r], sc[1][r]), fmaxf(sc[2][r], sc[3][r]));
            tm = fmaxf(tm, __shfl_xor(tm, 1));
            tm = fmaxf(tm, __shfl_xor(tm, 2));
            tm = fmaxf(tm, __shfl_xor(tm, 4));
            tm = fmaxf(tm, __shfl_xor(tm, 8));
            const float mn = fmaxf(m_run[r], tm);     // m_init=-1e30 keeps this finite
            const float alpha = __expf(m_run[r] - mn);
            float rs = 0.f;
#pragma unroll
            for (int nt = 0; nt < 4; ++nt) {
                const float p = __expf(sc[nt][r] - mn);   // exp(-inf)=0 for masked
                sc[nt][r] = p;
                rs += p;
            }
            rs += __shfl_xor(rs, 1);
            rs += __shfl_xor(rs, 2);
            rs += __shfl_xor(rs, 4);
            rs += __shfl_xor(rs, 8);
            l_run[r] = l_run[r] * alpha + rs;
            m_run[r] = mn;
#pragma unroll
            for (int nt = 0; nt < 4; ++nt) accO[nt][r] *= alpha;
        }

        // P: C-layout -> LDS -> A-layout (m120 pattern), per-wave buffer
#pragma unroll
        for (int nt = 0; nt < 4; ++nt)
#pragma unroll
            for (int r = 0; r < 4; ++r)
                Psh[w][quad * 4 + r][nt * 16 + l15] = f32_to_bf16(sc[nt][r]);
        __asm__ volatile("s_waitcnt lgkmcnt(0)" ::: "memory");  // wave-local RAW on Psh

        const bf16x8 p0 = *(const bf16x8*)&Psh[w][l15][quad * 8];
        const bf16x8 p1 = *(const bf16x8*)&Psh[w][l15][32 + quad * 8];
#pragma unroll
        for (int nt = 0; nt < 4; ++nt) {
            const bf16x8 v0 = *(const bf16x8*)&Vsh[nt * 16 + l15][quad * 8];
            const bf16x8 v1 = *(const bf16x8*)&Vsh[nt * 16 + l15][32 + quad * 8];
            accO[nt] = mfma_bf16(p0, v0, accO[nt]);
            accO[nt] = mfma_bf16(p1, v1, accO[nt]);
        }
    }

    // epilogue: normalize, write ctx in (B,S,D) bf16 (row-major for final GEMM)
#pragma unroll
    for (int r = 0; r < 4; ++r) {
        const float inv = 1.0f / l_run[r];
        const int gq = bi * SS + qrow0 + quad * 4 + r;
#pragma unroll
        for (int nt = 0; nt < 4; ++nt)
            ctx[(size_t)gq * DD + hi * DHH + nt * 16 + l15] = f32_to_bf16(accO[nt][r] * inv);
    }
}

// ---------------------------------------------------------------------------
// score_h0: head-0 raw masked scores via MFMA -> f32 [B][S][S] (d_out tail).
// Grid: B * (S/64 q-tiles) * 4 key-chunks; each block does 64q x 512keys.
// Masked entries get -1e18 (the reference constant) so a later full softmax
// reproduces reference semantics exactly (incl. fully-masked rows -> uniform).
// ---------------------------------------------------------------------------
__global__ __launch_bounds__(256) void score_h0(const unsigned short* __restrict__ q0,
                                                const unsigned short* __restrict__ k0,
                                                const int* __restrict__ mask,
                                                float* __restrict__ outp) {
    __shared__ __align__(16) unsigned short Ksh[64][72];

    const int kc = blockIdx.x & 3;             // key chunk (512 keys)
    const int qt = (blockIdx.x >> 2) & 31;     // q tile
    const int bi = blockIdx.x >> 7;            // batch

    const int t = threadIdx.x;
    const int lane = t & 63, w = t >> 6;
    const int l15 = lane & 15, quad = lane >> 4;

    const int qrow0 = qt * 64 + w * 16;
    const unsigned short* qp = q0 + ((size_t)bi * SS + qrow0) * DHH;
    const bf16x8 aq0 = *(const bf16x8*)(qp + (size_t)l15 * DHH + quad * 8);
    const bf16x8 aq1 = *(const bf16x8*)(qp + (size_t)l15 * DHH + 32 + quad * 8);

    const unsigned short* kp = k0 + (size_t)bi * SS * DHH;
    const int* mbase = mask + ((size_t)bi * SS + qrow0 + quad * 4) * SS;
    float* obase = outp + ((size_t)bi * SS + qrow0 + quad * 4) * SS;

    for (int kt = 0; kt < 8; ++kt) {
        const int key0 = kc * 512 + kt * 64;
        __syncthreads();
#pragma unroll
        for (int hf = 0; hf < 2; ++hf) {
            const int v = t + hf * 256;
            const int row = v >> 3, off = (v & 7) * 8;
            *(us8*)&Ksh[row][off] = *(const us8*)(kp + (size_t)(key0 + row) * DHH + off);
        }
        __syncthreads();

#pragma unroll
        for (int nt = 0; nt < 4; ++nt) {
            const bf16x8 b0 = *(const bf16x8*)&Ksh[nt * 16 + l15][quad * 8];
            const bf16x8 b1 = *(const bf16x8*)&Ksh[nt * 16 + l15][32 + quad * 8];
            f32x4 s4 = {};
            s4 = mfma_bf16(aq0, b0, s4);
            s4 = mfma_bf16(aq1, b1, s4);
#pragma unroll
            for (int r = 0; r < 4; ++r) {
                const int key = key0 + nt * 16 + l15;
                const float s = (mbase[(size_t)r * SS + key] != 0) ? -1e18f : s4[r];
                obase[(size_t)r * SS + key] = s;
            }
        }
    }
}

// ---------------------------------------------------------------------------
// norm_h0: in-place row softmax over [B*S][S] f32. One block per row.
// ---------------------------------------------------------------------------
__global__ __launch_bounds__(256) void norm_h0(float* __restrict__ scores) {
    __shared__ float wred[4];

    float* row = scores + (size_t)blockIdx.x * SS;
    const int t = threadIdx.x;

    float4 v0 = *(const float4*)&row[t * 4];
    float4 v1 = *(const float4*)&row[1024 + t * 4];

    float lmax = fmaxf(fmaxf(fmaxf(v0.x, v0.y), fmaxf(v0.z, v0.w)),
                       fmaxf(fmaxf(v1.x, v1.y), fmaxf(v1.z, v1.w)));
#pragma unroll
    for (int m = 1; m < 64; m <<= 1) lmax = fmaxf(lmax, __shfl_xor(lmax, m));
    if ((t & 63) == 0) wred[t >> 6] = lmax;
    __syncthreads();
    const float bmax = fmaxf(fmaxf(wred[0], wred[1]), fmaxf(wred[2], wred[3]));
    __syncthreads();

    v0.x = __expf(v0.x - bmax); v0.y = __expf(v0.y - bmax);
    v0.z = __expf(v0.z - bmax); v0.w = __expf(v0.w - bmax);
    v1.x = __expf(v1.x - bmax); v1.y = __expf(v1.y - bmax);
    v1.z = __expf(v1.z - bmax); v1.w = __expf(v1.w - bmax);

    float lsum = (v0.x + v0.y) + (v0.z + v0.w) + (v1.x + v1.y) + (v1.z + v1.w);
#pragma unroll
    for (int m = 1; m < 64; m <<= 1) lsum += __shfl_xor(lsum, m);
    if ((t & 63) == 0) wred[t >> 6] = lsum;
    __syncthreads();
    const float inv = 1.0f / (wred[0] + wred[1] + wred[2] + wred[3]);

    v0.x *= inv; v0.y *= inv; v0.z *= inv; v0.w *= inv;
    v1.x *= inv; v1.y *= inv; v1.z *= inv; v1.w *= inv;
    *(float4*)&row[t * 4] = v0;
    *(float4*)&row[1024 + t * 4] = v1;
}

// ---------------------------------------------------------------------------
// inputs: 0 key, 1 value, 2 query, 3 mask, 4 Wk, 5 bk, 6 Wv, 7 bv,
//         8 Wq, 9 bq, 10 Wo, 11 bo
// d_out: output (B*S*D f32) ++ top_attn (B*S*S f32)
//
// Scratch plan: qws/kws/vws/ctx (32 MB bf16) live inside d_out's top_attn
// region (only written at the very end by score_h0/norm_h0). d_ws holds the
// 1 MB head-0 q/k slices that survive the scratch clobber.
// ---------------------------------------------------------------------------
extern "C" void kernel_launch(void* const* d_in, const int* in_sizes, int n_in,
                              void* d_out, int out_size, void* d_ws, size_t ws_size,
                              hipStream_t stream) {
    const float* key_   = (const float*)d_in[0];
    const float* value_ = (const float*)d_in[1];
    const float* query_ = (const float*)d_in[2];
    const int*   mask_  = (const int*)d_in[3];
    const float* Wk = (const float*)d_in[4];
    const float* bk = (const float*)d_in[5];
    const float* Wv = (const float*)d_in[6];
    const float* bv = (const float*)d_in[7];
    const float* Wq = (const float*)d_in[8];
    const float* bq = (const float*)d_in[9];
    const float* Wo = (const float*)d_in[10];
    const float* bo = (const float*)d_in[11];

    constexpr size_t XS = (size_t)BB * SS * DD;   // 4194304 elements

    float* out_f = (float*)d_out;
    unsigned short* scratch = (unsigned short*)(out_f + XS);
    unsigned short* qws = scratch;            // (B,H,S,DH)
    unsigned short* kws = qws + XS;           // (B,H,S,DH)
    unsigned short* vws = kws + XS;           // (B,H,DH,S)
    unsigned short* ctx = vws + XS;           // (B,S,D)

    unsigned short* q0 = (unsigned short*)d_ws;        // [B][S][DH] head-0 q
    unsigned short* k0 = q0 + (size_t)BB * SS * DHH;   // [B][S][DH] head-0 k

    dim3 gg(BB * SS / 64, DD / 64);
    gemm_nt<0><<<gg, 256, 0, stream>>>(query_, Wq, bq, qws, 0.125f);  // 1/sqrt(DH) folded
    gemm_nt<0><<<gg, 256, 0, stream>>>(key_,   Wk, bk, kws, 1.0f);
    gemm_nt<1><<<gg, 256, 0, stream>>>(value_, Wv, bv, vws, 1.0f);    // v transposed

    // save head-0 q/k (contiguous slices) into d_ws before scratch is clobbered
    for (int b = 0; b < BB; ++b) {
        hipMemcpyAsync(q0 + (size_t)b * SS * DHH, qws + (size_t)(b * HH) * SS * DHH,
                       (size_t)SS * DHH * sizeof(unsigned short),
                       hipMemcpyDeviceToDevice, stream);
        hipMemcpyAsync(k0 + (size_t)b * SS * DHH, kws + (size_t)(b * HH) * SS * DHH,
                       (size_t)SS * DHH * sizeof(unsigned short),
                       hipMemcpyDeviceToDevice, stream);
    }

    flash_attn<<<BB * HH * (SS / 64), 256, 0, stream>>>(qws, kws, vws, mask_, ctx);

    gemm_nt<2><<<gg, 256, 0, stream>>>(ctx, Wo, bo, out_f, 1.0f);

    // LAST: overwrite the scratch region with head-0 scores, then softmax it
    score_h0<<<BB * 32 * 4, 256, 0, stream>>>(q0, k0, mask_, out_f + XS);
    norm_h0<<<BB * SS, 256, 0, stream>>>(out_f + XS);
}

// Round 4
// 398.546 us; speedup vs baseline: 1.6481x; 1.3372x over previous
//
#include <hip/hip_runtime.h>

// Problem constants: B=2, S=2048, D=1024, H=16, DH=64
constexpr int BB = 2, SS = 2048, DD = 1024, HH = 16, DHH = 64;

typedef __attribute__((ext_vector_type(4))) float f32x4;
typedef __attribute__((ext_vector_type(8))) __bf16 bf16x8;      // 4 VGPRs, MFMA A/B operand
typedef __attribute__((ext_vector_type(8))) unsigned short us8; // 16B staging vector

__device__ __forceinline__ unsigned short f32_to_bf16(float f) {
    unsigned int u = __float_as_uint(f);
    u += 0x7fffu + ((u >> 16) & 1u);   // round-to-nearest-even
    return (unsigned short)(u >> 16);
}

// packed f32x2 -> bf16x2 (RNE); gfx950 has v_cvt_pk_bf16_f32
__device__ __forceinline__ ushort2 pk_bf16(float a, float b) {
#if __has_builtin(__builtin_amdgcn_cvt_pk_bf16_f32)
    typedef __attribute__((ext_vector_type(2))) __bf16 bf16x2;
    bf16x2 r = __builtin_amdgcn_cvt_pk_bf16_f32(a, b);
    return *(ushort2*)&r;
#else
    ushort2 r; r.x = f32_to_bf16(a); r.y = f32_to_bf16(b); return r;
#endif
}
__device__ __forceinline__ ushort4 pk_bf16x4(float a, float b, float c, float d) {
    const ushort2 lo = pk_bf16(a, b), hi = pk_bf16(c, d);
    ushort4 r; r.x = lo.x; r.y = lo.y; r.z = hi.x; r.w = hi.y;
    return r;
}

__device__ __forceinline__ f32x4 mfma_bf16(bf16x8 a, bf16x8 b, f32x4 c) {
    return __builtin_amdgcn_mfma_f32_16x16x32_bf16(a, b, c, 0, 0, 0);
}

// ---------------------------------------------------------------------------
// mask_pack: int32 mask [B*S*S] -> bitmask [B*S*S/64] (bit j = chunk*64+j).
// One wave per 64-key chunk via __ballot.
// ---------------------------------------------------------------------------
__global__ __launch_bounds__(256) void mask_pack(const int* __restrict__ mask,
                                                 unsigned long long* __restrict__ pm) {
    const int t = threadIdx.x;
    const size_t chunk = (size_t)blockIdx.x * 4 + (t >> 6);
    const int lane = t & 63;
    const int v = mask[chunk * 64 + lane];
    const unsigned long long b = __ballot(v != 0);
    if (lane == 0) pm[chunk] = b;
}

// ---------------------------------------------------------------------------
// NT GEMM: C[m][n] = (sum_k A[m][k]*W[n][k] + bias[n]) * scale
// Tile 128x64 (MxN), BK=64, 4 waves in 2x2 (each 64x32). Grid 512 = 2/CU.
// W: N x K fp32, converted to bf16 in staging (v_cvt_pk_bf16_f32).
// MODE 0: A fp32; write bf16 (B,H,S,DH)     (q, k)
// MODE 1: A fp32; write bf16 (B,H,DH,S)     (v transposed for PV)
// MODE 2: A bf16; write fp32 M x N          (final output)
// ---------------------------------------------------------------------------
template <int MODE>
__global__ __launch_bounds__(256) void gemm_nt(const void* __restrict__ Ap,
                                               const float* __restrict__ W,
                                               const float* __restrict__ bias,
                                               void* __restrict__ outp,
                                               float scale) {
    constexpr int K = DD;
    __shared__ __align__(16) unsigned short Ash[128][72];  // +8 pad
    __shared__ __align__(16) unsigned short Bsh[64][72];

    const int m0 = blockIdx.x * 128;
    const int n0 = blockIdx.y * 64;
    const int t = threadIdx.x;
    const int lane = t & 63, w = t >> 6;
    const int l15 = lane & 15, quad = lane >> 4;
    const int wm = (w >> 1) * 64, wn = (w & 1) * 32;

    f32x4 acc[4][2] = {};

    for (int k0 = 0; k0 < K; k0 += 64) {
        __syncthreads();
        // B: 64x64 f32 -> bf16 (4 x float4 per thread)
#pragma unroll
        for (int j = 0; j < 4; ++j) {
            const int v = t + j * 256;
            const int row = v >> 4, c4 = (v & 15) * 4;
            const float4 wv = *(const float4*)&W[(size_t)(n0 + row) * K + k0 + c4];
            *(ushort4*)&Bsh[row][c4] = pk_bf16x4(wv.x, wv.y, wv.z, wv.w);
        }
        // A: 128x64
        if (MODE == 2) {
            const unsigned short* A = (const unsigned short*)Ap;
#pragma unroll
            for (int j = 0; j < 4; ++j) {
                const int v = t + j * 256;
                const int row = v >> 3, off = (v & 7) * 8;
                *(us8*)&Ash[row][off] = *(const us8*)&A[(size_t)(m0 + row) * K + k0 + off];
            }
        } else {
            const float* A = (const float*)Ap;
#pragma unroll
            for (int j = 0; j < 8; ++j) {
                const int v = t + j * 256;
                const int row = v >> 4, c4 = (v & 15) * 4;
                const float4 av = *(const float4*)&A[(size_t)(m0 + row) * K + k0 + c4];
                *(ushort4*)&Ash[row][c4] = pk_bf16x4(av.x, av.y, av.z, av.w);
            }
        }
        __syncthreads();

#pragma unroll
        for (int s = 0; s < 2; ++s) {
            bf16x8 af[4], bfr[2];
#pragma unroll
            for (int mi = 0; mi < 4; ++mi)
                af[mi] = *(const bf16x8*)&Ash[wm + mi * 16 + l15][s * 32 + quad * 8];
#pragma unroll
            for (int ni = 0; ni < 2; ++ni)
                bfr[ni] = *(const bf16x8*)&Bsh[wn + ni * 16 + l15][s * 32 + quad * 8];
#pragma unroll
            for (int mi = 0; mi < 4; ++mi)
#pragma unroll
                for (int ni = 0; ni < 2; ++ni)
                    acc[mi][ni] = mfma_bf16(af[mi], bfr[ni], acc[mi][ni]);
        }
    }

#pragma unroll
    for (int ni = 0; ni < 2; ++ni) {
        const int c = n0 + wn + ni * 16 + l15;
        const float bs = bias[c];
#pragma unroll
        for (int mi = 0; mi < 4; ++mi) {
#pragma unroll
            for (int r = 0; r < 4; ++r) {
                const int mrow = m0 + wm + mi * 16 + quad * 4 + r;
                const float val = (acc[mi][ni][r] + bs) * scale;
                if (MODE == 2) {
                    ((float*)outp)[(size_t)mrow * DD + c] = val;
                } else {
                    const int bi2 = mrow >> 11, si = mrow & (SS - 1);
                    const int hi2 = c >> 6, di = c & (DHH - 1);
                    unsigned short* o = (unsigned short*)outp;
                    if (MODE == 0)
                        o[((size_t)(bi2 * HH + hi2) * SS + si) * DHH + di] = f32_to_bf16(val);
                    else
                        o[((size_t)(bi2 * HH + hi2) * DHH + di) * SS + si] = f32_to_bf16(val);
                }
            }
        }
    }
}

// ---------------------------------------------------------------------------
// Flash attention v2 (S^T scheme): one workgroup per (b,h,64-q tile), 4 waves.
// Each lane owns ONE q-row (q = l15): QK^T computed transposed (A=K, B=Q) so
// the C layout gives col=q, row=key. Softmax = 15 in-lane max + 2 shfl_xor.
// P^T per lane is 4 consecutive keys -> packed ds_write_b64; PV uses A=V^T,
// B=P producing O^T (col=q) so alpha/l stay per-lane scalars.
// Scores are in log2e units (folded into q scale) -> exp2-based softmax.
// ---------------------------------------------------------------------------
__global__ __launch_bounds__(256) void flash_attn(const unsigned short* __restrict__ qws,
                                                  const unsigned short* __restrict__ kws,
                                                  const unsigned short* __restrict__ vws,
                                                  const unsigned long long* __restrict__ pm,
                                                  unsigned short* __restrict__ ctx) {
    __shared__ __align__(16) unsigned short Ksh[64][72];      // [key][d]
    __shared__ __align__(16) unsigned short Vsh[64][72];      // [d][key]
    __shared__ __align__(16) unsigned short Psh[4][16][72];   // per-wave [q][key]

    constexpr int NQT = SS / 64;
    const int qt = blockIdx.x % NQT;
    const int bh = blockIdx.x / NQT;
    const int bi = bh / HH, hi = bh % HH;

    const int t = threadIdx.x;
    const int lane = t & 63, w = t >> 6;
    const int l15 = lane & 15, quad = lane >> 4;
    const int sh4 = quad * 4;

    const unsigned short* qp = qws + (size_t)bh * SS * DHH;
    const unsigned short* kp = kws + (size_t)bh * SS * DHH;
    const unsigned short* vp = vws + (size_t)bh * DHH * SS;

    const int q_loc = qt * 64 + w * 16 + l15;     // this lane's q row
    const bf16x8 bq0 = *(const bf16x8*)(qp + (size_t)q_loc * DHH + quad * 8);
    const bf16x8 bq1 = *(const bf16x8*)(qp + (size_t)q_loc * DHH + 32 + quad * 8);

    const unsigned long long* pmrow = pm + ((size_t)bi * SS + q_loc) * (SS / 64);

    f32x4 accO[4] = {};                            // O^T: d = 16i + quad*4 + r, q = l15
    float m_run = -1e30f, l_run = 0.f;
    const float NEG_INF = -__builtin_inff();

    for (int kt = 0; kt < SS / 64; ++kt) {
        __syncthreads();   // prior iteration's LDS reads complete before restage
#pragma unroll
        for (int hf = 0; hf < 2; ++hf) {
            const int v = t + hf * 256;
            const int row = v >> 3, off = (v & 7) * 8;
            *(us8*)&Ksh[row][off] = *(const us8*)(kp + (size_t)(kt * 64 + row) * DHH + off);
            *(us8*)&Vsh[row][off] = *(const us8*)(vp + (size_t)row * SS + kt * 64 + off);
        }
        __syncthreads();

        // bitmask for this lane's q row, pre-shifted by quad*4
        const unsigned long long m64 = pmrow[kt];
        const unsigned int mlo = ((unsigned int)m64) >> sh4;
        const unsigned int mhi = ((unsigned int)(m64 >> 32)) >> sh4;

        // S^T: key = kt*64 + 16i + quad*4 + r, q = l15
        float sc[4][4];
#pragma unroll
        for (int i = 0; i < 4; ++i) {
            const bf16x8 ak0 = *(const bf16x8*)&Ksh[i * 16 + l15][quad * 8];
            const bf16x8 ak1 = *(const bf16x8*)&Ksh[i * 16 + l15][32 + quad * 8];
            f32x4 s4 = {};
            s4 = mfma_bf16(ak0, bq0, s4);
            s4 = mfma_bf16(ak1, bq1, s4);
            const unsigned int mw = (i & 2) ? mhi : mlo;
#pragma unroll
            for (int r = 0; r < 4; ++r)
                sc[i][r] = ((mw >> ((i & 1) * 16 + r)) & 1u) ? NEG_INF : s4[r];
        }

        // online softmax for q = l15 (base-2; scores carry log2e)
        float tm = sc[0][0];
#pragma unroll
        for (int i = 0; i < 4; ++i)
#pragma unroll
            for (int r = 0; r < 4; ++r) tm = fmaxf(tm, sc[i][r]);
        tm = fmaxf(tm, __shfl_xor(tm, 16));
        tm = fmaxf(tm, __shfl_xor(tm, 32));
        const float mn = fmaxf(m_run, tm);
        const float alpha = __builtin_amdgcn_exp2f(m_run - mn);
        float rs = 0.f;
#pragma unroll
        for (int i = 0; i < 4; ++i)
#pragma unroll
            for (int r = 0; r < 4; ++r) {
                const float p = __builtin_amdgcn_exp2f(sc[i][r] - mn);  // exp2(-inf)=0
                sc[i][r] = p;
                rs += p;
            }
        rs += __shfl_xor(rs, 16);
        rs += __shfl_xor(rs, 32);
        l_run = l_run * alpha + rs;
        m_run = mn;
#pragma unroll
        for (int i = 0; i < 4; ++i)
#pragma unroll
            for (int r = 0; r < 4; ++r) accO[i][r] *= alpha;

        // P store: lane's 4 consecutive keys -> one b64 per i (wave-private)
#pragma unroll
        for (int i = 0; i < 4; ++i)
            *(ushort4*)&Psh[w][l15][i * 16 + sh4] =
                pk_bf16x4(sc[i][0], sc[i][1], sc[i][2], sc[i][3]);
        __asm__ volatile("s_waitcnt lgkmcnt(0)" ::: "memory");  // wave-local RAW

        const bf16x8 p0 = *(const bf16x8*)&Psh[w][l15][quad * 8];
        const bf16x8 p1 = *(const bf16x8*)&Psh[w][l15][32 + quad * 8];
#pragma unroll
        for (int i = 0; i < 4; ++i) {
            const bf16x8 av0 = *(const bf16x8*)&Vsh[i * 16 + l15][quad * 8];
            const bf16x8 av1 = *(const bf16x8*)&Vsh[i * 16 + l15][32 + quad * 8];
            accO[i] = mfma_bf16(av0, p0, accO[i]);   // O^T[d][q]
            accO[i] = mfma_bf16(av1, p1, accO[i]);
        }
    }

    // epilogue: lane q = l15, d = 16i + quad*4 + {0..3} -> packed b64 stores
    const float inv = 1.0f / l_run;
    unsigned short* cb = ctx + ((size_t)(bi * SS) + qt * 64 + w * 16 + l15) * DD + hi * DHH;
#pragma unroll
    for (int i = 0; i < 4; ++i)
        *(ushort4*)&cb[i * 16 + sh4] = pk_bf16x4(accO[i][0] * inv, accO[i][1] * inv,
                                                 accO[i][2] * inv, accO[i][3] * inv);
}

// ---------------------------------------------------------------------------
// score_h0: head-0 raw masked scores via MFMA -> f32 [B][S][S] (d_out tail).
// Scores are log2e-scaled (q scale); masked -> -1e18; norm_h0 uses exp2.
// ---------------------------------------------------------------------------
__global__ __launch_bounds__(256) void score_h0(const unsigned short* __restrict__ q0,
                                                const unsigned short* __restrict__ k0,
                                                const int* __restrict__ mask,
                                                float* __restrict__ outp) {
    __shared__ __align__(16) unsigned short Ksh[64][72];

    const int kc = blockIdx.x & 3;             // key chunk (512 keys)
    const int qt = (blockIdx.x >> 2) & 31;     // q tile
    const int bi = blockIdx.x >> 7;            // batch

    const int t = threadIdx.x;
    const int lane = t & 63, w = t >> 6;
    const int l15 = lane & 15, quad = lane >> 4;

    const int qrow0 = qt * 64 + w * 16;
    const unsigned short* qp = q0 + ((size_t)bi * SS + qrow0) * DHH;
    const bf16x8 aq0 = *(const bf16x8*)(qp + (size_t)l15 * DHH + quad * 8);
    const bf16x8 aq1 = *(const bf16x8*)(qp + (size_t)l15 * DHH + 32 + quad * 8);

    const unsigned short* kp = k0 + (size_t)bi * SS * DHH;
    const int* mbase = mask + ((size_t)bi * SS + qrow0 + quad * 4) * SS;
    float* obase = outp + ((size_t)bi * SS + qrow0 + quad * 4) * SS;

    for (int kt = 0; kt < 8; ++kt) {
        const int key0 = kc * 512 + kt * 64;
        __syncthreads();
#pragma unroll
        for (int hf = 0; hf < 2; ++hf) {
            const int v = t + hf * 256;
            const int row = v >> 3, off = (v & 7) * 8;
            *(us8*)&Ksh[row][off] = *(const us8*)(kp + (size_t)(key0 + row) * DHH + off);
        }
        __syncthreads();

#pragma unroll
        for (int nt = 0; nt < 4; ++nt) {
            const bf16x8 b0 = *(const bf16x8*)&Ksh[nt * 16 + l15][quad * 8];
            const bf16x8 b1 = *(const bf16x8*)&Ksh[nt * 16 + l15][32 + quad * 8];
            f32x4 s4 = {};
            s4 = mfma_bf16(aq0, b0, s4);
            s4 = mfma_bf16(aq1, b1, s4);
#pragma unroll
            for (int r = 0; r < 4; ++r) {
                const int key = key0 + nt * 16 + l15;
                const float s = (mbase[(size_t)r * SS + key] != 0) ? -1e18f : s4[r];
                obase[(size_t)r * SS + key] = s;
            }
        }
    }
}

// ---------------------------------------------------------------------------
// norm_h0: in-place row softmax (base-2; scores carry log2e) over [B*S][S].
// ---------------------------------------------------------------------------
__global__ __launch_bounds__(256) void norm_h0(float* __restrict__ scores) {
    __shared__ float wred[4];

    float* row = scores + (size_t)blockIdx.x * SS;
    const int t = threadIdx.x;

    float4 v0 = *(const float4*)&row[t * 4];
    float4 v1 = *(const float4*)&row[1024 + t * 4];

    float lmax = fmaxf(fmaxf(fmaxf(v0.x, v0.y), fmaxf(v0.z, v0.w)),
                       fmaxf(fmaxf(v1.x, v1.y), fmaxf(v1.z, v1.w)));
#pragma unroll
    for (int m = 1; m < 64; m <<= 1) lmax = fmaxf(lmax, __shfl_xor(lmax, m));
    if ((t & 63) == 0) wred[t >> 6] = lmax;
    __syncthreads();
    const float bmax = fmaxf(fmaxf(wred[0], wred[1]), fmaxf(wred[2], wred[3]));
    __syncthreads();

    v0.x = __builtin_amdgcn_exp2f(v0.x - bmax); v0.y = __builtin_amdgcn_exp2f(v0.y - bmax);
    v0.z = __builtin_amdgcn_exp2f(v0.z - bmax); v0.w = __builtin_amdgcn_exp2f(v0.w - bmax);
    v1.x = __builtin_amdgcn_exp2f(v1.x - bmax); v1.y = __builtin_amdgcn_exp2f(v1.y - bmax);
    v1.z = __builtin_amdgcn_exp2f(v1.z - bmax); v1.w = __builtin_amdgcn_exp2f(v1.w - bmax);

    float lsum = (v0.x + v0.y) + (v0.z + v0.w) + (v1.x + v1.y) + (v1.z + v1.w);
#pragma unroll
    for (int m = 1; m < 64; m <<= 1) lsum += __shfl_xor(lsum, m);
    if ((t & 63) == 0) wred[t >> 6] = lsum;
    __syncthreads();
    const float inv = 1.0f / (wred[0] + wred[1] + wred[2] + wred[3]);

    v0.x *= inv; v0.y *= inv; v0.z *= inv; v0.w *= inv;
    v1.x *= inv; v1.y *= inv; v1.z *= inv; v1.w *= inv;
    *(float4*)&row[t * 4] = v0;
    *(float4*)&row[1024 + t * 4] = v1;
}

// ---------------------------------------------------------------------------
// inputs: 0 key, 1 value, 2 query, 3 mask, 4 Wk, 5 bk, 6 Wv, 7 bv,
//         8 Wq, 9 bq, 10 Wo, 11 bo
// d_out: output (B*S*D f32) ++ top_attn (B*S*S f32)
// Scratch: qws/kws/vws/ctx (32 MB bf16) inside d_out's top_attn region
// (overwritten at the very end). d_ws: head-0 q/k copies (1 MB) + packed
// mask bits (1 MB) = 2 MB.
// ---------------------------------------------------------------------------
extern "C" void kernel_launch(void* const* d_in, const int* in_sizes, int n_in,
                              void* d_out, int out_size, void* d_ws, size_t ws_size,
                              hipStream_t stream) {
    const float* key_   = (const float*)d_in[0];
    const float* value_ = (const float*)d_in[1];
    const float* query_ = (const float*)d_in[2];
    const int*   mask_  = (const int*)d_in[3];
    const float* Wk = (const float*)d_in[4];
    const float* bk = (const float*)d_in[5];
    const float* Wv = (const float*)d_in[6];
    const float* bv = (const float*)d_in[7];
    const float* Wq = (const float*)d_in[8];
    const float* bq = (const float*)d_in[9];
    const float* Wo = (const float*)d_in[10];
    const float* bo = (const float*)d_in[11];

    constexpr size_t XS = (size_t)BB * SS * DD;   // 4194304 elements

    float* out_f = (float*)d_out;
    unsigned short* scratch = (unsigned short*)(out_f + XS);
    unsigned short* qws = scratch;            // (B,H,S,DH)
    unsigned short* kws = qws + XS;           // (B,H,S,DH)
    unsigned short* vws = kws + XS;           // (B,H,DH,S)
    unsigned short* ctx = vws + XS;           // (B,S,D)

    unsigned short* q0 = (unsigned short*)d_ws;             // [B][S][DH] head-0 q
    unsigned short* k0 = q0 + (size_t)BB * SS * DHH;        // [B][S][DH] head-0 k
    unsigned long long* pm = (unsigned long long*)(k0 + (size_t)BB * SS * DHH); // 1 MB bits

    // pack mask to bits (used by flash)
    mask_pack<<<BB * SS * (SS / 64) / 4, 256, 0, stream>>>(mask_, pm);

    // q scale = 1/sqrt(DH) * log2(e)  -> exp2-based softmax downstream
    const float qscale = 0.125f * 1.4426950408889634f;

    dim3 gg(BB * SS / 128, DD / 64);
    gemm_nt<0><<<gg, 256, 0, stream>>>(query_, Wq, bq, qws, qscale);
    gemm_nt<0><<<gg, 256, 0, stream>>>(key_,   Wk, bk, kws, 1.0f);
    gemm_nt<1><<<gg, 256, 0, stream>>>(value_, Wv, bv, vws, 1.0f);   // v transposed

    // save head-0 q/k before the scratch region is clobbered at the end
    for (int b = 0; b < BB; ++b) {
        hipMemcpyAsync(q0 + (size_t)b * SS * DHH, qws + (size_t)(b * HH) * SS * DHH,
                       (size_t)SS * DHH * sizeof(unsigned short),
                       hipMemcpyDeviceToDevice, stream);
        hipMemcpyAsync(k0 + (size_t)b * SS * DHH, kws + (size_t)(b * HH) * SS * DHH,
                       (size_t)SS * DHH * sizeof(unsigned short),
                       hipMemcpyDeviceToDevice, stream);
    }

    flash_attn<<<BB * HH * (SS / 64), 256, 0, stream>>>(qws, kws, vws, pm, ctx);

    gemm_nt<2><<<gg, 256, 0, stream>>>(ctx, Wo, bo, out_f, 1.0f);

    // LAST: overwrite the scratch region with head-0 scores, then softmax it
    score_h0<<<BB * 32 * 4, 256, 0, stream>>>(q0, k0, mask_, out_f + XS);
    norm_h0<<<BB * SS, 256, 0, stream>>>(out_f + XS);
}

// Round 5
// 382.154 us; speedup vs baseline: 1.7187x; 1.0429x over previous
//
#include <hip/hip_runtime.h>

// Problem constants: B=2, S=2048, D=1024, H=16, DH=64
constexpr int BB = 2, SS = 2048, DD = 1024, HH = 16, DHH = 64;

typedef __attribute__((ext_vector_type(4))) float f32x4;
typedef __attribute__((ext_vector_type(8))) __bf16 bf16x8;      // 4 VGPRs, MFMA A/B operand
typedef __attribute__((ext_vector_type(8))) unsigned short us8; // 16B staging vector

__device__ __forceinline__ unsigned short f32_to_bf16(float f) {
    unsigned int u = __float_as_uint(f);
    u += 0x7fffu + ((u >> 16) & 1u);   // round-to-nearest-even
    return (unsigned short)(u >> 16);
}

// packed f32x2 -> bf16x2 (RNE); gfx950 has v_cvt_pk_bf16_f32
__device__ __forceinline__ ushort2 pk_bf16(float a, float b) {
#if __has_builtin(__builtin_amdgcn_cvt_pk_bf16_f32)
    typedef __attribute__((ext_vector_type(2))) __bf16 bf16x2;
    bf16x2 r = __builtin_amdgcn_cvt_pk_bf16_f32(a, b);
    return *(ushort2*)&r;
#else
    ushort2 r; r.x = f32_to_bf16(a); r.y = f32_to_bf16(b); return r;
#endif
}
__device__ __forceinline__ ushort4 pk_bf16x4(float a, float b, float c, float d) {
    const ushort2 lo = pk_bf16(a, b), hi = pk_bf16(c, d);
    ushort4 r; r.x = lo.x; r.y = lo.y; r.z = hi.x; r.w = hi.y;
    return r;
}

__device__ __forceinline__ f32x4 mfma_bf16(bf16x8 a, bf16x8 b, f32x4 c) {
    return __builtin_amdgcn_mfma_f32_16x16x32_bf16(a, b, c, 0, 0, 0);
}

// ---------------------------------------------------------------------------
// cvt_bf16: fp32 -> bf16, 8 elements/thread (two float4 -> one us8 store)
// ---------------------------------------------------------------------------
__global__ __launch_bounds__(256) void cvt_bf16(const float* __restrict__ src,
                                                unsigned short* __restrict__ dst) {
    const size_t i = ((size_t)blockIdx.x * 256 + threadIdx.x) * 8;
    const float4 a = *(const float4*)(src + i);
    const float4 b = *(const float4*)(src + i + 4);
    ushort4 lo = pk_bf16x4(a.x, a.y, a.z, a.w);
    ushort4 hi = pk_bf16x4(b.x, b.y, b.z, b.w);
    us8 o;
    o[0] = lo.x; o[1] = lo.y; o[2] = lo.z; o[3] = lo.w;
    o[4] = hi.x; o[5] = hi.y; o[6] = hi.z; o[7] = hi.w;
    *(us8*)(dst + i) = o;
}

// ---------------------------------------------------------------------------
// mask_pack: int32 mask [B*S*S] -> bitmask [B*S*S/64] (bit j = chunk*64+j).
// ---------------------------------------------------------------------------
__global__ __launch_bounds__(256) void mask_pack(const int* __restrict__ mask,
                                                 unsigned long long* __restrict__ pm) {
    const int t = threadIdx.x;
    const size_t chunk = (size_t)blockIdx.x * 4 + (t >> 6);
    const int lane = t & 63;
    const int v = mask[chunk * 64 + lane];
    const unsigned long long b = __ballot(v != 0);
    if (lane == 0) pm[chunk] = b;
}

// ---------------------------------------------------------------------------
// NT GEMM, all-bf16 inputs: C[m][n] = (sum_k A[m][k]*W[n][k] + bias[n])*scale
// A: M x K bf16 row-major. W: N x K bf16 row-major (pre-converted).
// Tile 128x64 (MxN), BK=64, 4 waves 2x2 (each 64x32). Grid 512 = 2/CU.
// MODE 0: write bf16 (B,H,S,DH)   (q, k)
// MODE 1: write bf16 (B,H,DH,S)   (v transposed for PV)
// MODE 2: write fp32 M x N        (final output)
// MFMA 16x16x32 layouts (m89/m91): A/B idx=lane&15,k=quad*8+j;
// C/D col=lane&15,row=quad*4+reg.
// ---------------------------------------------------------------------------
template <int MODE>
__global__ __launch_bounds__(256) void gemm_nt(const unsigned short* __restrict__ A,
                                               const unsigned short* __restrict__ Wb,
                                               const float* __restrict__ bias,
                                               void* __restrict__ outp,
                                               float scale) {
    constexpr int K = DD;
    __shared__ __align__(16) unsigned short Ash[128][72];  // +8 pad
    __shared__ __align__(16) unsigned short Bsh[64][72];

    const int m0 = blockIdx.x * 128;
    const int n0 = blockIdx.y * 64;
    const int t = threadIdx.x;
    const int lane = t & 63, w = t >> 6;
    const int l15 = lane & 15, quad = lane >> 4;
    const int wm = (w >> 1) * 64, wn = (w & 1) * 32;

    f32x4 acc[4][2] = {};

    for (int k0 = 0; k0 < K; k0 += 64) {
        __syncthreads();
#pragma unroll
        for (int j = 0; j < 4; ++j) {              // A: 128x64 bf16
            const int v = t + j * 256;
            const int row = v >> 3, off = (v & 7) * 8;
            *(us8*)&Ash[row][off] = *(const us8*)&A[(size_t)(m0 + row) * K + k0 + off];
        }
#pragma unroll
        for (int j = 0; j < 2; ++j) {              // B: 64x64 bf16
            const int v = t + j * 256;
            const int row = v >> 3, off = (v & 7) * 8;
            *(us8*)&Bsh[row][off] = *(const us8*)&Wb[(size_t)(n0 + row) * K + k0 + off];
        }
        __syncthreads();

#pragma unroll
        for (int s = 0; s < 2; ++s) {
            bf16x8 af[4], bfr[2];
#pragma unroll
            for (int mi = 0; mi < 4; ++mi)
                af[mi] = *(const bf16x8*)&Ash[wm + mi * 16 + l15][s * 32 + quad * 8];
#pragma unroll
            for (int ni = 0; ni < 2; ++ni)
                bfr[ni] = *(const bf16x8*)&Bsh[wn + ni * 16 + l15][s * 32 + quad * 8];
#pragma unroll
            for (int mi = 0; mi < 4; ++mi)
#pragma unroll
                for (int ni = 0; ni < 2; ++ni)
                    acc[mi][ni] = mfma_bf16(af[mi], bfr[ni], acc[mi][ni]);
        }
    }

#pragma unroll
    for (int ni = 0; ni < 2; ++ni) {
        const int c = n0 + wn + ni * 16 + l15;
        const float bs = bias[c];
#pragma unroll
        for (int mi = 0; mi < 4; ++mi) {
#pragma unroll
            for (int r = 0; r < 4; ++r) {
                const int mrow = m0 + wm + mi * 16 + quad * 4 + r;
                const float val = (acc[mi][ni][r] + bs) * scale;
                if (MODE == 2) {
                    ((float*)outp)[(size_t)mrow * DD + c] = val;
                } else {
                    const int bi2 = mrow >> 11, si = mrow & (SS - 1);
                    const int hi2 = c >> 6, di = c & (DHH - 1);
                    unsigned short* o = (unsigned short*)outp;
                    if (MODE == 0)
                        o[((size_t)(bi2 * HH + hi2) * SS + si) * DHH + di] = f32_to_bf16(val);
                    else
                        o[((size_t)(bi2 * HH + hi2) * DHH + di) * SS + si] = f32_to_bf16(val);
                }
            }
        }
    }
}

// ---------------------------------------------------------------------------
// Flash attention v2 (S^T scheme) — unchanged from R3 (verified).
// ---------------------------------------------------------------------------
__global__ __launch_bounds__(256) void flash_attn(const unsigned short* __restrict__ qws,
                                                  const unsigned short* __restrict__ kws,
                                                  const unsigned short* __restrict__ vws,
                                                  const unsigned long long* __restrict__ pm,
                                                  unsigned short* __restrict__ ctx) {
    __shared__ __align__(16) unsigned short Ksh[64][72];      // [key][d]
    __shared__ __align__(16) unsigned short Vsh[64][72];      // [d][key]
    __shared__ __align__(16) unsigned short Psh[4][16][72];   // per-wave [q][key]

    constexpr int NQT = SS / 64;
    const int qt = blockIdx.x % NQT;
    const int bh = blockIdx.x / NQT;
    const int bi = bh / HH, hi = bh % HH;

    const int t = threadIdx.x;
    const int lane = t & 63, w = t >> 6;
    const int l15 = lane & 15, quad = lane >> 4;
    const int sh4 = quad * 4;

    const unsigned short* qp = qws + (size_t)bh * SS * DHH;
    const unsigned short* kp = kws + (size_t)bh * SS * DHH;
    const unsigned short* vp = vws + (size_t)bh * DHH * SS;

    const int q_loc = qt * 64 + w * 16 + l15;     // this lane's q row
    const bf16x8 bq0 = *(const bf16x8*)(qp + (size_t)q_loc * DHH + quad * 8);
    const bf16x8 bq1 = *(const bf16x8*)(qp + (size_t)q_loc * DHH + 32 + quad * 8);

    const unsigned long long* pmrow = pm + ((size_t)bi * SS + q_loc) * (SS / 64);

    f32x4 accO[4] = {};                            // O^T: d = 16i + quad*4 + r, q = l15
    float m_run = -1e30f, l_run = 0.f;
    const float NEG_INF = -__builtin_inff();

    for (int kt = 0; kt < SS / 64; ++kt) {
        __syncthreads();   // prior iteration's LDS reads complete before restage
#pragma unroll
        for (int hf = 0; hf < 2; ++hf) {
            const int v = t + hf * 256;
            const int row = v >> 3, off = (v & 7) * 8;
            *(us8*)&Ksh[row][off] = *(const us8*)(kp + (size_t)(kt * 64 + row) * DHH + off);
            *(us8*)&Vsh[row][off] = *(const us8*)(vp + (size_t)row * SS + kt * 64 + off);
        }
        __syncthreads();

        const unsigned long long m64 = pmrow[kt];
        const unsigned int mlo = ((unsigned int)m64) >> sh4;
        const unsigned int mhi = ((unsigned int)(m64 >> 32)) >> sh4;

        // S^T: key = kt*64 + 16i + quad*4 + r, q = l15
        float sc[4][4];
#pragma unroll
        for (int i = 0; i < 4; ++i) {
            const bf16x8 ak0 = *(const bf16x8*)&Ksh[i * 16 + l15][quad * 8];
            const bf16x8 ak1 = *(const bf16x8*)&Ksh[i * 16 + l15][32 + quad * 8];
            f32x4 s4 = {};
            s4 = mfma_bf16(ak0, bq0, s4);
            s4 = mfma_bf16(ak1, bq1, s4);
            const unsigned int mw = (i & 2) ? mhi : mlo;
#pragma unroll
            for (int r = 0; r < 4; ++r)
                sc[i][r] = ((mw >> ((i & 1) * 16 + r)) & 1u) ? NEG_INF : s4[r];
        }

        // online softmax for q = l15 (base-2; scores carry log2e)
        float tm = sc[0][0];
#pragma unroll
        for (int i = 0; i < 4; ++i)
#pragma unroll
            for (int r = 0; r < 4; ++r) tm = fmaxf(tm, sc[i][r]);
        tm = fmaxf(tm, __shfl_xor(tm, 16));
        tm = fmaxf(tm, __shfl_xor(tm, 32));
        const float mn = fmaxf(m_run, tm);
        const float alpha = __builtin_amdgcn_exp2f(m_run - mn);
        float rs = 0.f;
#pragma unroll
        for (int i = 0; i < 4; ++i)
#pragma unroll
            for (int r = 0; r < 4; ++r) {
                const float p = __builtin_amdgcn_exp2f(sc[i][r] - mn);  // exp2(-inf)=0
                sc[i][r] = p;
                rs += p;
            }
        rs += __shfl_xor(rs, 16);
        rs += __shfl_xor(rs, 32);
        l_run = l_run * alpha + rs;
        m_run = mn;
#pragma unroll
        for (int i = 0; i < 4; ++i)
#pragma unroll
            for (int r = 0; r < 4; ++r) accO[i][r] *= alpha;

        // P store: lane's 4 consecutive keys -> one b64 per i (wave-private)
#pragma unroll
        for (int i = 0; i < 4; ++i)
            *(ushort4*)&Psh[w][l15][i * 16 + sh4] =
                pk_bf16x4(sc[i][0], sc[i][1], sc[i][2], sc[i][3]);
        __asm__ volatile("s_waitcnt lgkmcnt(0)" ::: "memory");  // wave-local RAW

        const bf16x8 p0 = *(const bf16x8*)&Psh[w][l15][quad * 8];
        const bf16x8 p1 = *(const bf16x8*)&Psh[w][l15][32 + quad * 8];
#pragma unroll
        for (int i = 0; i < 4; ++i) {
            const bf16x8 av0 = *(const bf16x8*)&Vsh[i * 16 + l15][quad * 8];
            const bf16x8 av1 = *(const bf16x8*)&Vsh[i * 16 + l15][32 + quad * 8];
            accO[i] = mfma_bf16(av0, p0, accO[i]);   // O^T[d][q]
            accO[i] = mfma_bf16(av1, p1, accO[i]);
        }
    }

    // epilogue: lane q = l15, d = 16i + quad*4 + {0..3} -> packed b64 stores
    const float inv = 1.0f / l_run;
    unsigned short* cb = ctx + ((size_t)(bi * SS) + qt * 64 + w * 16 + l15) * DD + hi * DHH;
#pragma unroll
    for (int i = 0; i < 4; ++i)
        *(ushort4*)&cb[i * 16 + sh4] = pk_bf16x4(accO[i][0] * inv, accO[i][1] * inv,
                                                 accO[i][2] * inv, accO[i][3] * inv);
}

// ---------------------------------------------------------------------------
// score_h0: head-0 raw masked scores via MFMA -> f32 [B][S][S] (d_out tail).
// Scores are log2e-scaled (q scale); masked -> -1e18; norm_h0 uses exp2.
// ---------------------------------------------------------------------------
__global__ __launch_bounds__(256) void score_h0(const unsigned short* __restrict__ q0,
                                                const unsigned short* __restrict__ k0,
                                                const int* __restrict__ mask,
                                                float* __restrict__ outp) {
    __shared__ __align__(16) unsigned short Ksh[64][72];

    const int kc = blockIdx.x & 3;             // key chunk (512 keys)
    const int qt = (blockIdx.x >> 2) & 31;     // q tile
    const int bi = blockIdx.x >> 7;            // batch

    const int t = threadIdx.x;
    const int lane = t & 63, w = t >> 6;
    const int l15 = lane & 15, quad = lane >> 4;

    const int qrow0 = qt * 64 + w * 16;
    const unsigned short* qp = q0 + ((size_t)bi * SS + qrow0) * DHH;
    const bf16x8 aq0 = *(const bf16x8*)(qp + (size_t)l15 * DHH + quad * 8);
    const bf16x8 aq1 = *(const bf16x8*)(qp + (size_t)l15 * DHH + 32 + quad * 8);

    const unsigned short* kp = k0 + (size_t)bi * SS * DHH;
    const int* mbase = mask + ((size_t)bi * SS + qrow0 + quad * 4) * SS;
    float* obase = outp + ((size_t)bi * SS + qrow0 + quad * 4) * SS;

    for (int kt = 0; kt < 8; ++kt) {
        const int key0 = kc * 512 + kt * 64;
        __syncthreads();
#pragma unroll
        for (int hf = 0; hf < 2; ++hf) {
            const int v = t + hf * 256;
            const int row = v >> 3, off = (v & 7) * 8;
            *(us8*)&Ksh[row][off] = *(const us8*)(kp + (size_t)(key0 + row) * DHH + off);
        }
        __syncthreads();

#pragma unroll
        for (int nt = 0; nt < 4; ++nt) {
            const bf16x8 b0 = *(const bf16x8*)&Ksh[nt * 16 + l15][quad * 8];
            const bf16x8 b1 = *(const bf16x8*)&Ksh[nt * 16 + l15][32 + quad * 8];
            f32x4 s4 = {};
            s4 = mfma_bf16(aq0, b0, s4);
            s4 = mfma_bf16(aq1, b1, s4);
#pragma unroll
            for (int r = 0; r < 4; ++r) {
                const int key = key0 + nt * 16 + l15;
                const float s = (mbase[(size_t)r * SS + key] != 0) ? -1e18f : s4[r];
                obase[(size_t)r * SS + key] = s;
            }
        }
    }
}

// ---------------------------------------------------------------------------
// norm_h0: in-place row softmax (base-2; scores carry log2e) over [B*S][S].
// ---------------------------------------------------------------------------
__global__ __launch_bounds__(256) void norm_h0(float* __restrict__ scores) {
    __shared__ float wred[4];

    float* row = scores + (size_t)blockIdx.x * SS;
    const int t = threadIdx.x;

    float4 v0 = *(const float4*)&row[t * 4];
    float4 v1 = *(const float4*)&row[1024 + t * 4];

    float lmax = fmaxf(fmaxf(fmaxf(v0.x, v0.y), fmaxf(v0.z, v0.w)),
                       fmaxf(fmaxf(v1.x, v1.y), fmaxf(v1.z, v1.w)));
#pragma unroll
    for (int m = 1; m < 64; m <<= 1) lmax = fmaxf(lmax, __shfl_xor(lmax, m));
    if ((t & 63) == 0) wred[t >> 6] = lmax;
    __syncthreads();
    const float bmax = fmaxf(fmaxf(wred[0], wred[1]), fmaxf(wred[2], wred[3]));
    __syncthreads();

    v0.x = __builtin_amdgcn_exp2f(v0.x - bmax); v0.y = __builtin_amdgcn_exp2f(v0.y - bmax);
    v0.z = __builtin_amdgcn_exp2f(v0.z - bmax); v0.w = __builtin_amdgcn_exp2f(v0.w - bmax);
    v1.x = __builtin_amdgcn_exp2f(v1.x - bmax); v1.y = __builtin_amdgcn_exp2f(v1.y - bmax);
    v1.z = __builtin_amdgcn_exp2f(v1.z - bmax); v1.w = __builtin_amdgcn_exp2f(v1.w - bmax);

    float lsum = (v0.x + v0.y) + (v0.z + v0.w) + (v1.x + v1.y) + (v1.z + v1.w);
#pragma unroll
    for (int m = 1; m < 64; m <<= 1) lsum += __shfl_xor(lsum, m);
    if ((t & 63) == 0) wred[t >> 6] = lsum;
    __syncthreads();
    const float inv = 1.0f / (wred[0] + wred[1] + wred[2] + wred[3]);

    v0.x *= inv; v0.y *= inv; v0.z *= inv; v0.w *= inv;
    v1.x *= inv; v1.y *= inv; v1.z *= inv; v1.w *= inv;
    *(float4*)&row[t * 4] = v0;
    *(float4*)&row[1024 + t * 4] = v1;
}

// ---------------------------------------------------------------------------
// inputs: 0 key, 1 value, 2 query, 3 mask, 4 Wk, 5 bk, 6 Wv, 7 bv,
//         8 Wq, 9 bq, 10 Wo, 11 bo
// d_out: output (B*S*D f32, 16 MB) ++ top_attn (B*S*S f32, 32 MB)
//
// Buffer choreography (d_ws use stays 2 MB: pm + head-0 q/k):
//   ctx region (free till flash)       <- Wq/Wk/Wv bf16 (6 MB)
//   out_f[0:16MB] (free till out-GEMM) <- Xq, Xk bf16
//   kws region (free till gemm-k)      <- Xv bf16  (gemm-v runs BEFORE gemm-k)
//   qws region (free after flash)      <- Wo bf16
// All GEMMs are pure bf16.
// ---------------------------------------------------------------------------
extern "C" void kernel_launch(void* const* d_in, const int* in_sizes, int n_in,
                              void* d_out, int out_size, void* d_ws, size_t ws_size,
                              hipStream_t stream) {
    const float* key_   = (const float*)d_in[0];
    const float* value_ = (const float*)d_in[1];
    const float* query_ = (const float*)d_in[2];
    const int*   mask_  = (const int*)d_in[3];
    const float* Wk = (const float*)d_in[4];
    const float* bk = (const float*)d_in[5];
    const float* Wv = (const float*)d_in[6];
    const float* bv = (const float*)d_in[7];
    const float* Wq = (const float*)d_in[8];
    const float* bq = (const float*)d_in[9];
    const float* Wo = (const float*)d_in[10];
    const float* bo = (const float*)d_in[11];

    constexpr size_t XS  = (size_t)BB * SS * DD;  // 4194304 elements
    constexpr size_t WSZ = (size_t)DD * DD;       // 1048576 elements

    float* out_f = (float*)d_out;
    unsigned short* scratch = (unsigned short*)(out_f + XS);
    unsigned short* qws = scratch;            // (B,H,S,DH)
    unsigned short* kws = qws + XS;           // (B,H,S,DH)
    unsigned short* vws = kws + XS;           // (B,H,DH,S)
    unsigned short* ctx = vws + XS;           // (B,S,D) — holds Wq/Wk/Wv bf16 pre-flash

    unsigned short* q0 = (unsigned short*)d_ws;             // [B][S][DH] head-0 q
    unsigned short* k0 = q0 + (size_t)BB * SS * DHH;        // [B][S][DH] head-0 k
    unsigned long long* pm = (unsigned long long*)(k0 + (size_t)BB * SS * DHH);

    // bf16 staging areas in dead regions
    unsigned short* Xq  = (unsigned short*)out_f;           // 8 MB
    unsigned short* Xk  = Xq + XS;                          // 8 MB
    unsigned short* Xv  = kws;                              // kws free till gemm-k
    unsigned short* Wqb = ctx;                              // ctx free till flash
    unsigned short* Wkb = Wqb + WSZ;
    unsigned short* Wvb = Wkb + WSZ;
    unsigned short* Wob = qws;                              // qws free after flash

    mask_pack<<<BB * SS * (SS / 64) / 4, 256, 0, stream>>>(mask_, pm);

    cvt_bf16<<<XS / 2048, 256, 0, stream>>>(query_, Xq);
    cvt_bf16<<<XS / 2048, 256, 0, stream>>>(key_,   Xk);
    cvt_bf16<<<XS / 2048, 256, 0, stream>>>(value_, Xv);
    cvt_bf16<<<WSZ / 2048, 256, 0, stream>>>(Wq, Wqb);
    cvt_bf16<<<WSZ / 2048, 256, 0, stream>>>(Wk, Wkb);
    cvt_bf16<<<WSZ / 2048, 256, 0, stream>>>(Wv, Wvb);

    // q scale = 1/sqrt(DH) * log2(e)  -> exp2-based softmax downstream
    const float qscale = 0.125f * 1.4426950408889634f;

    dim3 gg(BB * SS / 128, DD / 64);
    gemm_nt<0><<<gg, 256, 0, stream>>>(Xq, Wqb, bq, qws, qscale);
    gemm_nt<1><<<gg, 256, 0, stream>>>(Xv, Wvb, bv, vws, 1.0f);   // before gemm-k (Xv in kws)
    gemm_nt<0><<<gg, 256, 0, stream>>>(Xk, Wkb, bk, kws, 1.0f);

    // save head-0 q/k before the scratch region is clobbered at the end
    for (int b = 0; b < BB; ++b) {
        hipMemcpyAsync(q0 + (size_t)b * SS * DHH, qws + (size_t)(b * HH) * SS * DHH,
                       (size_t)SS * DHH * sizeof(unsigned short),
                       hipMemcpyDeviceToDevice, stream);
        hipMemcpyAsync(k0 + (size_t)b * SS * DHH, kws + (size_t)(b * HH) * SS * DHH,
                       (size_t)SS * DHH * sizeof(unsigned short),
                       hipMemcpyDeviceToDevice, stream);
    }

    flash_attn<<<BB * HH * (SS / 64), 256, 0, stream>>>(qws, kws, vws, pm, ctx);

    // qws is consumed; reuse it for Wo bf16, then the final GEMM
    cvt_bf16<<<WSZ / 2048, 256, 0, stream>>>(Wo, Wob);
    gemm_nt<2><<<gg, 256, 0, stream>>>(ctx, Wob, bo, out_f, 1.0f);

    // LAST: overwrite the scratch region with head-0 scores, then softmax it
    score_h0<<<BB * 32 * 4, 256, 0, stream>>>(q0, k0, mask_, out_f + XS);
    norm_h0<<<BB * SS, 256, 0, stream>>>(out_f + XS);
}

// Round 6
// 373.704 us; speedup vs baseline: 1.7576x; 1.0226x over previous
//
#include <hip/hip_runtime.h>

// Problem constants: B=2, S=2048, D=1024, H=16, DH=64
constexpr int BB = 2, SS = 2048, DD = 1024, HH = 16, DHH = 64;

typedef __attribute__((ext_vector_type(4))) float f32x4;
typedef __attribute__((ext_vector_type(8))) __bf16 bf16x8;      // 4 VGPRs, MFMA A/B operand
typedef __attribute__((ext_vector_type(8))) unsigned short us8; // 16B staging vector

__device__ __forceinline__ unsigned short f32_to_bf16(float f) {
    unsigned int u = __float_as_uint(f);
    u += 0x7fffu + ((u >> 16) & 1u);   // round-to-nearest-even
    return (unsigned short)(u >> 16);
}

// packed f32x2 -> bf16x2 (RNE); gfx950 has v_cvt_pk_bf16_f32
__device__ __forceinline__ ushort2 pk_bf16(float a, float b) {
#if __has_builtin(__builtin_amdgcn_cvt_pk_bf16_f32)
    typedef __attribute__((ext_vector_type(2))) __bf16 bf16x2;
    bf16x2 r = __builtin_amdgcn_cvt_pk_bf16_f32(a, b);
    return *(ushort2*)&r;
#else
    ushort2 r; r.x = f32_to_bf16(a); r.y = f32_to_bf16(b); return r;
#endif
}
__device__ __forceinline__ ushort4 pk_bf16x4(float a, float b, float c, float d) {
    const ushort2 lo = pk_bf16(a, b), hi = pk_bf16(c, d);
    ushort4 r; r.x = lo.x; r.y = lo.y; r.z = hi.x; r.w = hi.y;
    return r;
}

__device__ __forceinline__ f32x4 mfma_bf16(bf16x8 a, bf16x8 b, f32x4 c) {
    return __builtin_amdgcn_mfma_f32_16x16x32_bf16(a, b, c, 0, 0, 0);
}

// ---------------------------------------------------------------------------
// cvt_bf16: fp32 -> bf16, 8 elements/thread
// ---------------------------------------------------------------------------
__global__ __launch_bounds__(256) void cvt_bf16(const float* __restrict__ src,
                                                unsigned short* __restrict__ dst) {
    const size_t i = ((size_t)blockIdx.x * 256 + threadIdx.x) * 8;
    const float4 a = *(const float4*)(src + i);
    const float4 b = *(const float4*)(src + i + 4);
    ushort4 lo = pk_bf16x4(a.x, a.y, a.z, a.w);
    ushort4 hi = pk_bf16x4(b.x, b.y, b.z, b.w);
    us8 o;
    o[0] = lo.x; o[1] = lo.y; o[2] = lo.z; o[3] = lo.w;
    o[4] = hi.x; o[5] = hi.y; o[6] = hi.z; o[7] = hi.w;
    *(us8*)(dst + i) = o;
}

// ---------------------------------------------------------------------------
// mask_pack: int32 mask [B*S*S] -> bitmask [B*S*S/64] (bit j = chunk*64+j).
// ---------------------------------------------------------------------------
__global__ __launch_bounds__(256) void mask_pack(const int* __restrict__ mask,
                                                 unsigned long long* __restrict__ pm) {
    const int t = threadIdx.x;
    const size_t chunk = (size_t)blockIdx.x * 4 + (t >> 6);
    const int lane = t & 63;
    const int v = mask[chunk * 64 + lane];
    const unsigned long long b = __ballot(v != 0);
    if (lane == 0) pm[chunk] = b;
}

// ---------------------------------------------------------------------------
// NT GEMM, all-bf16 inputs (unchanged from R4 — verified).
// ---------------------------------------------------------------------------
template <int MODE>
__global__ __launch_bounds__(256) void gemm_nt(const unsigned short* __restrict__ A,
                                               const unsigned short* __restrict__ Wb,
                                               const float* __restrict__ bias,
                                               void* __restrict__ outp,
                                               float scale) {
    constexpr int K = DD;
    __shared__ __align__(16) unsigned short Ash[128][72];  // +8 pad
    __shared__ __align__(16) unsigned short Bsh[64][72];

    const int m0 = blockIdx.x * 128;
    const int n0 = blockIdx.y * 64;
    const int t = threadIdx.x;
    const int lane = t & 63, w = t >> 6;
    const int l15 = lane & 15, quad = lane >> 4;
    const int wm = (w >> 1) * 64, wn = (w & 1) * 32;

    f32x4 acc[4][2] = {};

    for (int k0 = 0; k0 < K; k0 += 64) {
        __syncthreads();
#pragma unroll
        for (int j = 0; j < 4; ++j) {              // A: 128x64 bf16
            const int v = t + j * 256;
            const int row = v >> 3, off = (v & 7) * 8;
            *(us8*)&Ash[row][off] = *(const us8*)&A[(size_t)(m0 + row) * K + k0 + off];
        }
#pragma unroll
        for (int j = 0; j < 2; ++j) {              // B: 64x64 bf16
            const int v = t + j * 256;
            const int row = v >> 3, off = (v & 7) * 8;
            *(us8*)&Bsh[row][off] = *(const us8*)&Wb[(size_t)(n0 + row) * K + k0 + off];
        }
        __syncthreads();

#pragma unroll
        for (int s = 0; s < 2; ++s) {
            bf16x8 af[4], bfr[2];
#pragma unroll
            for (int mi = 0; mi < 4; ++mi)
                af[mi] = *(const bf16x8*)&Ash[wm + mi * 16 + l15][s * 32 + quad * 8];
#pragma unroll
            for (int ni = 0; ni < 2; ++ni)
                bfr[ni] = *(const bf16x8*)&Bsh[wn + ni * 16 + l15][s * 32 + quad * 8];
#pragma unroll
            for (int mi = 0; mi < 4; ++mi)
#pragma unroll
                for (int ni = 0; ni < 2; ++ni)
                    acc[mi][ni] = mfma_bf16(af[mi], bfr[ni], acc[mi][ni]);
        }
    }

#pragma unroll
    for (int ni = 0; ni < 2; ++ni) {
        const int c = n0 + wn + ni * 16 + l15;
        const float bs = bias[c];
#pragma unroll
        for (int mi = 0; mi < 4; ++mi) {
#pragma unroll
            for (int r = 0; r < 4; ++r) {
                const int mrow = m0 + wm + mi * 16 + quad * 4 + r;
                const float val = (acc[mi][ni][r] + bs) * scale;
                if (MODE == 2) {
                    ((float*)outp)[(size_t)mrow * DD + c] = val;
                } else {
                    const int bi2 = mrow >> 11, si = mrow & (SS - 1);
                    const int hi2 = c >> 6, di = c & (DHH - 1);
                    unsigned short* o = (unsigned short*)outp;
                    if (MODE == 0)
                        o[((size_t)(bi2 * HH + hi2) * SS + si) * DHH + di] = f32_to_bf16(val);
                    else
                        o[((size_t)(bi2 * HH + hi2) * DHH + di) * SS + si] = f32_to_bf16(val);
                }
            }
        }
    }
}

// ---------------------------------------------------------------------------
// Flash attention v3: 128 q-rows per block (2 groups of 64), 4 waves.
// Per k-tile, K/V fragments are loaded ONCE and reused for both q-groups;
// Psh is reused sequentially across groups (same-wave DS ops are ordered).
// Per-tile math identical to the verified R3/R4 kernel.
// ---------------------------------------------------------------------------
__global__ __launch_bounds__(256) void flash_attn(const unsigned short* __restrict__ qws,
                                                  const unsigned short* __restrict__ kws,
                                                  const unsigned short* __restrict__ vws,
                                                  const unsigned long long* __restrict__ pm,
                                                  unsigned short* __restrict__ ctx) {
    __shared__ __align__(16) unsigned short Ksh[64][72];      // [key][d]
    __shared__ __align__(16) unsigned short Vsh[64][72];      // [d][key]
    __shared__ __align__(16) unsigned short Psh[4][16][72];   // per-wave [q][key], reused per g

    constexpr int NQT = SS / 128;
    const int qt = blockIdx.x % NQT;
    const int bh = blockIdx.x / NQT;
    const int bi = bh / HH, hi = bh % HH;

    const int t = threadIdx.x;
    const int lane = t & 63, w = t >> 6;
    const int l15 = lane & 15, quad = lane >> 4;
    const int sh4 = quad * 4;

    const unsigned short* qp = qws + (size_t)bh * SS * DHH;
    const unsigned short* kp = kws + (size_t)bh * SS * DHH;
    const unsigned short* vp = vws + (size_t)bh * DHH * SS;

    // two q-groups per wave
    bf16x8 bq0[2], bq1[2];
    const unsigned long long* pmrow[2];
#pragma unroll
    for (int g = 0; g < 2; ++g) {
        const int q_loc = qt * 128 + g * 64 + w * 16 + l15;
        bq0[g] = *(const bf16x8*)(qp + (size_t)q_loc * DHH + quad * 8);
        bq1[g] = *(const bf16x8*)(qp + (size_t)q_loc * DHH + 32 + quad * 8);
        pmrow[g] = pm + ((size_t)bi * SS + q_loc) * (SS / 64);
    }

    f32x4 accO[2][4] = {};                         // O^T per group: d = 16i+quad*4+r, q = l15
    float m_run[2] = {-1e30f, -1e30f}, l_run[2] = {0.f, 0.f};
    const float NEG_INF = -__builtin_inff();

    for (int kt = 0; kt < SS / 64; ++kt) {
        __syncthreads();   // prior iteration's LDS reads complete before restage
#pragma unroll
        for (int hf = 0; hf < 2; ++hf) {
            const int v = t + hf * 256;
            const int row = v >> 3, off = (v & 7) * 8;
            *(us8*)&Ksh[row][off] = *(const us8*)(kp + (size_t)(kt * 64 + row) * DHH + off);
            *(us8*)&Vsh[row][off] = *(const us8*)(vp + (size_t)row * SS + kt * 64 + off);
        }
        __syncthreads();

        // K/V fragments: load once, reuse for both q-groups
        bf16x8 ak0[4], ak1[4], av0[4], av1[4];
#pragma unroll
        for (int i = 0; i < 4; ++i) {
            ak0[i] = *(const bf16x8*)&Ksh[i * 16 + l15][quad * 8];
            ak1[i] = *(const bf16x8*)&Ksh[i * 16 + l15][32 + quad * 8];
            av0[i] = *(const bf16x8*)&Vsh[i * 16 + l15][quad * 8];
            av1[i] = *(const bf16x8*)&Vsh[i * 16 + l15][32 + quad * 8];
        }

#pragma unroll
        for (int g = 0; g < 2; ++g) {
            const unsigned long long m64 = pmrow[g][kt];
            const unsigned int mlo = ((unsigned int)m64) >> sh4;
            const unsigned int mhi = ((unsigned int)(m64 >> 32)) >> sh4;

            // S^T: key = kt*64 + 16i + quad*4 + r, q = l15
            float sc[4][4];
#pragma unroll
            for (int i = 0; i < 4; ++i) {
                f32x4 s4 = {};
                s4 = mfma_bf16(ak0[i], bq0[g], s4);
                s4 = mfma_bf16(ak1[i], bq1[g], s4);
                const unsigned int mw = (i & 2) ? mhi : mlo;
#pragma unroll
                for (int r = 0; r < 4; ++r)
                    sc[i][r] = ((mw >> ((i & 1) * 16 + r)) & 1u) ? NEG_INF : s4[r];
            }

            // online softmax for q = l15 (base-2; scores carry log2e)
            float tm = sc[0][0];
#pragma unroll
            for (int i = 0; i < 4; ++i)
#pragma unroll
                for (int r = 0; r < 4; ++r) tm = fmaxf(tm, sc[i][r]);
            tm = fmaxf(tm, __shfl_xor(tm, 16));
            tm = fmaxf(tm, __shfl_xor(tm, 32));
            const float mn = fmaxf(m_run[g], tm);
            const float alpha = __builtin_amdgcn_exp2f(m_run[g] - mn);
            float rs = 0.f;
#pragma unroll
            for (int i = 0; i < 4; ++i)
#pragma unroll
                for (int r = 0; r < 4; ++r) {
                    const float p = __builtin_amdgcn_exp2f(sc[i][r] - mn);
                    sc[i][r] = p;
                    rs += p;
                }
            rs += __shfl_xor(rs, 16);
            rs += __shfl_xor(rs, 32);
            l_run[g] = l_run[g] * alpha + rs;
            m_run[g] = mn;
#pragma unroll
            for (int i = 0; i < 4; ++i)
#pragma unroll
                for (int r = 0; r < 4; ++r) accO[g][i][r] *= alpha;

            // P store: lane's 4 consecutive keys -> one b64 per i (wave-private)
#pragma unroll
            for (int i = 0; i < 4; ++i)
                *(ushort4*)&Psh[w][l15][i * 16 + sh4] =
                    pk_bf16x4(sc[i][0], sc[i][1], sc[i][2], sc[i][3]);
            __asm__ volatile("s_waitcnt lgkmcnt(0)" ::: "memory");  // wave-local RAW

            const bf16x8 p0 = *(const bf16x8*)&Psh[w][l15][quad * 8];
            const bf16x8 p1 = *(const bf16x8*)&Psh[w][l15][32 + quad * 8];
#pragma unroll
            for (int i = 0; i < 4; ++i) {
                accO[g][i] = mfma_bf16(av0[i], p0, accO[g][i]);   // O^T[d][q]
                accO[g][i] = mfma_bf16(av1[i], p1, accO[g][i]);
            }
        }
    }

    // epilogue per group
#pragma unroll
    for (int g = 0; g < 2; ++g) {
        const float inv = 1.0f / l_run[g];
        unsigned short* cb = ctx + ((size_t)(bi * SS) + qt * 128 + g * 64 + w * 16 + l15) * DD
                                 + hi * DHH;
#pragma unroll
        for (int i = 0; i < 4; ++i)
            *(ushort4*)&cb[i * 16 + sh4] = pk_bf16x4(accO[g][i][0] * inv, accO[g][i][1] * inv,
                                                     accO[g][i][2] * inv, accO[g][i][3] * inv);
    }
}

// ---------------------------------------------------------------------------
// score_h0 v2: head-0 raw masked scores (S^T scheme) + per-chunk online
// (m, l) stats. Grid: B * 32 q-tiles * 4 key-chunks; block = 64q x 512keys.
// Lane owns q = l15; its 16-key subsets reduce in-lane, quad-merged (LSE) at
// the end. Masked -> -1e18 (reference constant). Scores carry log2e.
// ---------------------------------------------------------------------------
__global__ __launch_bounds__(256) void score_h0(const unsigned short* __restrict__ q0,
                                                const unsigned short* __restrict__ k0,
                                                const unsigned long long* __restrict__ pm,
                                                float* __restrict__ outp,
                                                float2* __restrict__ stats) {
    __shared__ __align__(16) unsigned short Ksh[64][72];

    const int kc = blockIdx.x & 3;             // key chunk (512 keys)
    const int qt = (blockIdx.x >> 2) & 31;     // q tile
    const int bi = blockIdx.x >> 7;            // batch

    const int t = threadIdx.x;
    const int lane = t & 63, w = t >> 6;
    const int l15 = lane & 15, quad = lane >> 4;
    const int sh4 = quad * 4;

    const int q = qt * 64 + w * 16 + l15;      // this lane's q row
    const unsigned short* qp = q0 + ((size_t)bi * SS + q) * DHH;
    const bf16x8 bq0 = *(const bf16x8*)(qp + quad * 8);
    const bf16x8 bq1 = *(const bf16x8*)(qp + 32 + quad * 8);

    const unsigned short* kp = k0 + (size_t)bi * SS * DHH;
    const unsigned long long* pmq = pm + ((size_t)bi * SS + q) * (SS / 64);
    float* orow = outp + ((size_t)bi * SS + q) * SS;

    float m_l = -1e30f, l_l = 0.f;

    for (int kt = 0; kt < 8; ++kt) {
        const int key0 = kc * 512 + kt * 64;
        __syncthreads();
#pragma unroll
        for (int hf = 0; hf < 2; ++hf) {
            const int v = t + hf * 256;
            const int row = v >> 3, off = (v & 7) * 8;
            *(us8*)&Ksh[row][off] = *(const us8*)(kp + (size_t)(key0 + row) * DHH + off);
        }
        __syncthreads();

        const unsigned long long m64 = pmq[kc * 8 + kt];
        const unsigned int mlo = ((unsigned int)m64) >> sh4;
        const unsigned int mhi = ((unsigned int)(m64 >> 32)) >> sh4;

        float sc[4][4];
        float lm = -1e30f;
#pragma unroll
        for (int i = 0; i < 4; ++i) {
            const bf16x8 ak0 = *(const bf16x8*)&Ksh[i * 16 + l15][quad * 8];
            const bf16x8 ak1 = *(const bf16x8*)&Ksh[i * 16 + l15][32 + quad * 8];
            f32x4 s4 = {};
            s4 = mfma_bf16(ak0, bq0, s4);
            s4 = mfma_bf16(ak1, bq1, s4);
            const unsigned int mw = (i & 2) ? mhi : mlo;
            float4 ov;
#pragma unroll
            for (int r = 0; r < 4; ++r) {
                const float s = ((mw >> ((i & 1) * 16 + r)) & 1u) ? -1e18f : s4[r];
                sc[i][r] = s;
                lm = fmaxf(lm, s);
            }
            ov.x = sc[i][0]; ov.y = sc[i][1]; ov.z = sc[i][2]; ov.w = sc[i][3];
            *(float4*)&orow[key0 + i * 16 + sh4] = ov;
        }

        // lane-local online update over this tile's 16 scores
        const float mn = fmaxf(m_l, lm);
        float rs = 0.f;
#pragma unroll
        for (int i = 0; i < 4; ++i)
#pragma unroll
            for (int r = 0; r < 4; ++r) rs += __builtin_amdgcn_exp2f(sc[i][r] - mn);
        l_l = l_l * __builtin_amdgcn_exp2f(m_l - mn) + rs;
        m_l = mn;
    }

    // merge the 4 quads owning this q-row (lanes l, l^16, l^32, l^48): LSE-merge
#pragma unroll
    for (int d = 16; d <= 32; d <<= 1) {
        const float mo = __shfl_xor(m_l, d);
        const float lo = __shfl_xor(l_l, d);
        const float mn = fmaxf(m_l, mo);
        l_l = l_l * __builtin_amdgcn_exp2f(m_l - mn) + lo * __builtin_amdgcn_exp2f(mo - mn);
        m_l = mn;
    }
    if (quad == 0) {
        float2 st; st.x = m_l; st.y = l_l;
        stats[((size_t)(bi * 4 + kc)) * SS + q] = st;
    }
}

// ---------------------------------------------------------------------------
// scale_h0: scores -> probs using per-chunk stats. One block per row,
// 8 elements/thread (pure stream). p = 2^(s - M) / L.
// ---------------------------------------------------------------------------
__global__ __launch_bounds__(256) void scale_h0(float* __restrict__ scores,
                                                const float2* __restrict__ stats) {
    const int bi = blockIdx.x >> 11;           // row = bi*S + si
    const int si = blockIdx.x & (SS - 1);
    const int t = threadIdx.x;

    // merge 4 chunk stats for this row
    float M = -1e30f, L = 0.f;
#pragma unroll
    for (int c = 0; c < 4; ++c) {
        const float2 st = stats[((size_t)(bi * 4 + c)) * SS + si];
        const float mn = fmaxf(M, st.x);
        L = L * __builtin_amdgcn_exp2f(M - mn) + st.y * __builtin_amdgcn_exp2f(st.x - mn);
        M = mn;
    }
    const float inv = 1.0f / L;

    float* row = scores + (size_t)blockIdx.x * SS;
    const int base = t * 8;
    float4 a = *(const float4*)&row[base];
    float4 b = *(const float4*)&row[base + 4];
    a.x = __builtin_amdgcn_exp2f(a.x - M) * inv;
    a.y = __builtin_amdgcn_exp2f(a.y - M) * inv;
    a.z = __builtin_amdgcn_exp2f(a.z - M) * inv;
    a.w = __builtin_amdgcn_exp2f(a.w - M) * inv;
    b.x = __builtin_amdgcn_exp2f(b.x - M) * inv;
    b.y = __builtin_amdgcn_exp2f(b.y - M) * inv;
    b.z = __builtin_amdgcn_exp2f(b.z - M) * inv;
    b.w = __builtin_amdgcn_exp2f(b.w - M) * inv;
    *(float4*)&row[base] = a;
    *(float4*)&row[base + 4] = b;
}

// ---------------------------------------------------------------------------
// inputs: 0 key, 1 value, 2 query, 3 mask, 4 Wk, 5 bk, 6 Wv, 7 bv,
//         8 Wq, 9 bq, 10 Wo, 11 bo
// d_out: output (B*S*D f32, 16 MB) ++ top_attn (B*S*S f32, 32 MB)
// d_ws (~2.13 MB): head-0 q/k (1 MB) + packed mask bits (1 MB) + stats (128 KB)
// ---------------------------------------------------------------------------
extern "C" void kernel_launch(void* const* d_in, const int* in_sizes, int n_in,
                              void* d_out, int out_size, void* d_ws, size_t ws_size,
                              hipStream_t stream) {
    const float* key_   = (const float*)d_in[0];
    const float* value_ = (const float*)d_in[1];
    const float* query_ = (const float*)d_in[2];
    const int*   mask_  = (const int*)d_in[3];
    const float* Wk = (const float*)d_in[4];
    const float* bk = (const float*)d_in[5];
    const float* Wv = (const float*)d_in[6];
    const float* bv = (const float*)d_in[7];
    const float* Wq = (const float*)d_in[8];
    const float* bq = (const float*)d_in[9];
    const float* Wo = (const float*)d_in[10];
    const float* bo = (const float*)d_in[11];

    constexpr size_t XS  = (size_t)BB * SS * DD;  // 4194304 elements
    constexpr size_t WSZ = (size_t)DD * DD;       // 1048576 elements

    float* out_f = (float*)d_out;
    unsigned short* scratch = (unsigned short*)(out_f + XS);
    unsigned short* qws = scratch;            // (B,H,S,DH)
    unsigned short* kws = qws + XS;           // (B,H,S,DH)
    unsigned short* vws = kws + XS;           // (B,H,DH,S)
    unsigned short* ctx = vws + XS;           // (B,S,D) — holds Wq/Wk/Wv bf16 pre-flash

    unsigned short* q0 = (unsigned short*)d_ws;             // [B][S][DH] head-0 q
    unsigned short* k0 = q0 + (size_t)BB * SS * DHH;        // [B][S][DH] head-0 k
    unsigned long long* pm = (unsigned long long*)(k0 + (size_t)BB * SS * DHH); // 1 MB
    float2* stats = (float2*)(pm + (size_t)BB * SS * (SS / 64));                // 128 KB

    // bf16 staging areas in dead regions
    unsigned short* Xq  = (unsigned short*)out_f;           // 8 MB
    unsigned short* Xk  = Xq + XS;                          // 8 MB
    unsigned short* Xv  = kws;                              // kws free till gemm-k
    unsigned short* Wqb = ctx;                              // ctx free till flash
    unsigned short* Wkb = Wqb + WSZ;
    unsigned short* Wvb = Wkb + WSZ;
    unsigned short* Wob = qws;                              // qws free after flash

    mask_pack<<<BB * SS * (SS / 64) / 4, 256, 0, stream>>>(mask_, pm);

    cvt_bf16<<<XS / 2048, 256, 0, stream>>>(query_, Xq);
    cvt_bf16<<<XS / 2048, 256, 0, stream>>>(key_,   Xk);
    cvt_bf16<<<XS / 2048, 256, 0, stream>>>(value_, Xv);
    cvt_bf16<<<WSZ / 2048, 256, 0, stream>>>(Wq, Wqb);
    cvt_bf16<<<WSZ / 2048, 256, 0, stream>>>(Wk, Wkb);
    cvt_bf16<<<WSZ / 2048, 256, 0, stream>>>(Wv, Wvb);

    // q scale = 1/sqrt(DH) * log2(e)  -> exp2-based softmax downstream
    const float qscale = 0.125f * 1.4426950408889634f;

    dim3 gg(BB * SS / 128, DD / 64);
    gemm_nt<0><<<gg, 256, 0, stream>>>(Xq, Wqb, bq, qws, qscale);
    gemm_nt<1><<<gg, 256, 0, stream>>>(Xv, Wvb, bv, vws, 1.0f);   // before gemm-k (Xv in kws)
    gemm_nt<0><<<gg, 256, 0, stream>>>(Xk, Wkb, bk, kws, 1.0f);

    // save head-0 q/k before the scratch region is clobbered at the end
    for (int b = 0; b < BB; ++b) {
        hipMemcpyAsync(q0 + (size_t)b * SS * DHH, qws + (size_t)(b * HH) * SS * DHH,
                       (size_t)SS * DHH * sizeof(unsigned short),
                       hipMemcpyDeviceToDevice, stream);
        hipMemcpyAsync(k0 + (size_t)b * SS * DHH, kws + (size_t)(b * HH) * SS * DHH,
                       (size_t)SS * DHH * sizeof(unsigned short),
                       hipMemcpyDeviceToDevice, stream);
    }

    flash_attn<<<BB * HH * (SS / 128), 256, 0, stream>>>(qws, kws, vws, pm, ctx);

    // qws is consumed; reuse it for Wo bf16, then the final GEMM
    cvt_bf16<<<WSZ / 2048, 256, 0, stream>>>(Wo, Wob);
    gemm_nt<2><<<gg, 256, 0, stream>>>(ctx, Wob, bo, out_f, 1.0f);

    // LAST: overwrite the scratch region with head-0 scores, then scale in place
    score_h0<<<BB * 32 * 4, 256, 0, stream>>>(q0, k0, pm, out_f + XS, stats);
    scale_h0<<<BB * SS, 256, 0, stream>>>(out_f + XS, stats);
}